// Round 1
// 480.094 us; speedup vs baseline: 1.2188x; 1.2188x over previous
//
#include <hip/hip_runtime.h>
#include <hip/hip_bf16.h>
#include <stdint.h>

// ---- types ----
typedef __bf16 bf16x8 __attribute__((ext_vector_type(8)));
typedef float  floatx4 __attribute__((ext_vector_type(4)));

#define NEG_BIG (-1e30f)   // finite sentinel: exp(NEG_BIG - m) == 0

// async global->LDS, 16B per lane; LDS dest = wave-uniform base + lane*16
#define GLD16(g, l) __builtin_amdgcn_global_load_lds(                         \
    (__attribute__((address_space(1))) void*)(g),                             \
    (__attribute__((address_space(3))) void*)(l), 16, 0, 0)

// convert 16 fp32 -> 16 bf16, store 32B to LDS
__device__ __forceinline__ void cvt16(const float* __restrict__ s,
                                      __hip_bfloat16* __restrict__ d) {
    float4 f[4];
#pragma unroll
    for (int i = 0; i < 4; i++) f[i] = ((const float4*)s)[i];
    union { __hip_bfloat16 h[16]; uint4 u[2]; } o;
#pragma unroll
    for (int i = 0; i < 4; i++) {
        o.h[4 * i + 0] = __float2bfloat16(f[i].x);
        o.h[4 * i + 1] = __float2bfloat16(f[i].y);
        o.h[4 * i + 2] = __float2bfloat16(f[i].z);
        o.h[4 * i + 3] = __float2bfloat16(f[i].w);
    }
    ((uint4*)d)[0] = o.u[0];
    ((uint4*)d)[1] = o.u[1];
}

// ============================================================================
// Fused fp32->bf16 convert of up to 3 arrays (grid-stride, 8 elems/thread).
// All lengths must be multiples of 8.
// ============================================================================
__global__ __launch_bounds__(256)
void cvt3_f32_bf16(const float* __restrict__ a, size_t na8,
                   const float* __restrict__ b, size_t nb8,
                   const float* __restrict__ c, size_t nc8,
                   __hip_bfloat16* __restrict__ da,
                   __hip_bfloat16* __restrict__ db,
                   __hip_bfloat16* __restrict__ dc)
{
    const size_t total  = na8 + nb8 + nc8;
    const size_t stride = (size_t)gridDim.x * blockDim.x;
    for (size_t idx = (size_t)blockIdx.x * blockDim.x + threadIdx.x;
         idx < total; idx += stride) {
        const float* s; __hip_bfloat16* d; size_t o;
        if (idx < na8)            { s = a; d = da; o = idx; }
        else if (idx < na8 + nb8) { s = b; d = db; o = idx - na8; }
        else                      { s = c; d = dc; o = idx - na8 - nb8; }
        const float4 f0 = ((const float4*)s)[o * 2 + 0];
        const float4 f1 = ((const float4*)s)[o * 2 + 1];
        union { __hip_bfloat16 h[8]; uint4 u; } z;
        z.h[0] = __float2bfloat16(f0.x); z.h[1] = __float2bfloat16(f0.y);
        z.h[2] = __float2bfloat16(f0.z); z.h[3] = __float2bfloat16(f0.w);
        z.h[4] = __float2bfloat16(f1.x); z.h[5] = __float2bfloat16(f1.y);
        z.h[6] = __float2bfloat16(f1.z); z.h[7] = __float2bfloat16(f1.w);
        ((uint4*)d)[o] = z.u;
    }
}

// ============================================================================
// NT GEMM: C[M,N] = A[M,K] * B[N,K]^T + bias[N].  A fp32/bf16 (template),
// B fp32/bf16 (template), fp32 bias. OUT_F32: C stored fp32 else bf16.
// 128x128 tile, BK=32, 256 threads (4 waves, 2x2 wave grid, 4x4 MFMAs each).
// bf16 operands stage via global_load_lds width=16 (m97 structure).
// ============================================================================
template <bool A_F32, bool B_F32, bool OUT_F32>
__global__ __launch_bounds__(256, 2)
void gemm_nt_bias(const void* __restrict__ Av, const void* __restrict__ Bv,
                  const float* __restrict__ bias, void* __restrict__ Cv,
                  int M, int N, int K, int lda, int ldb)
{
    __shared__ __align__(16) __hip_bfloat16 Asm[128 * 32];
    __shared__ __align__(16) __hip_bfloat16 Bsm[128 * 32];
    const int m0   = blockIdx.y * 128;
    const int n0   = blockIdx.x * 128;
    const int t    = threadIdx.x;
    const int wave = t >> 6, lane = t & 63;
    const int quad = lane >> 4, l16 = lane & 15;
    const int wr   = wave >> 1, wc = wave & 1;   // wave sub-tile 64x64

    floatx4 zero = {0.f, 0.f, 0.f, 0.f};
    floatx4 acc[4][4];
    for (int i = 0; i < 4; i++)
        for (int j = 0; j < 4; j++) acc[i][j] = zero;

    for (int k0 = 0; k0 < K; k0 += 32) {
        // ---- stage A tile (128 x 32) ----
        if (A_F32) {
            const float* A = (const float*)Av;
            const int row = t >> 1, half = t & 1;     // 16 floats per thread
            cvt16(A + (size_t)(m0 + row) * lda + k0 + half * 16,
                  Asm + row * 32 + half * 16);
        } else {
            const __hip_bfloat16* A = (const __hip_bfloat16*)Av;
            for (int j = 0; j < 2; ++j) {
                const int chunk = (wave * 2 + j) * 64 + lane;   // 0..511
                const int row   = chunk >> 2;
                const int kc    = chunk & 3;
                GLD16(A + (size_t)(m0 + row) * lda + k0 + kc * 8,
                      Asm + (wave * 2 + j) * 512);
            }
        }
        // ---- stage B tile (128 x 32) ----
        if (B_F32) {
            const float* B = (const float*)Bv;
            const int row = t >> 1, half = t & 1;
            cvt16(B + (size_t)(n0 + row) * ldb + k0 + half * 16,
                  Bsm + row * 32 + half * 16);
        } else {
            const __hip_bfloat16* B = (const __hip_bfloat16*)Bv;
            for (int j = 0; j < 2; ++j) {
                const int chunk = (wave * 2 + j) * 64 + lane;
                const int row   = chunk >> 2;
                const int kc    = chunk & 3;
                GLD16(B + (size_t)(n0 + row) * ldb + k0 + kc * 8,
                      Bsm + (wave * 2 + j) * 512);
            }
        }
        __syncthreads();

        bf16x8 af[4], bf[4];
        for (int i = 0; i < 4; i++) {
            af[i] = *(const bf16x8*)(Asm + (wr * 64 + i * 16 + l16) * 32 + quad * 8);
            bf[i] = *(const bf16x8*)(Bsm + (wc * 64 + i * 16 + l16) * 32 + quad * 8);
        }
        for (int mi = 0; mi < 4; mi++)
            for (int ni = 0; ni < 4; ni++)
                acc[mi][ni] = __builtin_amdgcn_mfma_f32_16x16x32_bf16(
                    af[mi], bf[ni], acc[mi][ni], 0, 0, 0);
        __syncthreads();
    }

    // epilogue: C/D layout row = quad*4 + reg, col = l16
    for (int mi = 0; mi < 4; mi++) {
        const int row = m0 + wr * 64 + mi * 16 + quad * 4;
        for (int ni = 0; ni < 4; ni++) {
            const int col = n0 + wc * 64 + ni * 16 + l16;
            const float bv = bias[col];
            for (int r = 0; r < 4; r++) {
                const float v = acc[mi][ni][r] + bv;
                if (OUT_F32)
                    ((float*)Cv)[(size_t)(row + r) * N + col] = v;
                else
                    ((__hip_bfloat16*)Cv)[(size_t)(row + r) * N + col] =
                        __float2bfloat16(v);
            }
        }
    }
}

// ============================================================================
// V permutation (module's double-reshape):
//   V[b,h,s',d'] = v0[b, (s'&7)*128 + h*8 + (d'>>4), (s'>>3)*16 + (d'&15)]
// v0 = QKV cols [4096,6144). Output blocked+transposed:
//   Vpt[b][h][sb][hd][ss]  (sb = s'/32, ss = s'%32) -> each kv tile contiguous.
// ============================================================================
__global__ __launch_bounds__(256)
void permute_v(const __hip_bfloat16* __restrict__ QKV,
               __hip_bfloat16* __restrict__ Vpt)
{
    __shared__ __align__(16) __hip_bfloat16 S[64 * 64];
    const int blk = blockIdx.x;
    const int sb = blk & 31, h = (blk >> 5) & 15, b = blk >> 9;
    const int t = threadIdx.x;

    for (int j = 0; j < 2; j++) {
        const int chunk = j * 256 + t;          // 0..511 (16B each)
        const int lrow  = chunk >> 3;           // 8 chunks per 64-elem row
        const int lcol  = (chunk & 7) * 8;
        const int r8 = lrow >> 3, jj = lrow & 7;
        const int srow = r8 * 128 + h * 8 + jj;
        const int scol = sb * 64 + lcol;
        *(uint4*)(S + chunk * 8) =
            *(const uint4*)(QKV + ((size_t)(b * 1024) + srow) * 6144 + 4096 + scol);
    }
    __syncthreads();

    const size_t obase = (((size_t)(b * 16 + h)) * 32 + sb) * 4096;
    for (int i = 0; i < 16; i++) {
        const int lin = t + 256 * i;            // coalesced writes
        const int hd = lin >> 5, ss = lin & 31;
        Vpt[obase + lin] =
            S[((ss & 7) * 8 + (hd >> 4)) * 64 + (ss >> 3) * 16 + (hd & 15)];
    }
}

// ============================================================================
// Causal flash attention. Block = 64 q-rows (4 waves x 16), kv tile = 32.
// Q,K from QKV; V from Vpt. Output into QKV's dead V-columns (stride 6144,
// col offset 4096) -- those columns are never read again (Vpt holds V).
// ============================================================================
__global__ __launch_bounds__(256, 2)
void flash_attn(const __hip_bfloat16* __restrict__ QKV,
                const __hip_bfloat16* __restrict__ Vpt,
                __hip_bfloat16* __restrict__ O)   // == QKV buffer
{
    __shared__ __align__(16) __hip_bfloat16 Kt[32 * 128];  // [kv][hd]
    __shared__ __align__(16) __hip_bfloat16 Vt[128 * 32];  // [hd][kv]
    __shared__ __align__(16) __hip_bfloat16 Pl[64 * 32];   // [qrow][kv]
    const int b = blockIdx.y >> 4, h = blockIdx.y & 15;
    const int qb = blockIdx.x * 64;
    const int t = threadIdx.x;
    const int wave = t >> 6, lane = t & 63;
    const int quad = lane >> 4, l16 = lane & 15;
    const float scale = 0.08838834764831845f;   // 128^-0.5

    // Q fragments (A-layout: row=l16, k=quad*8+j), direct from global
    bf16x8 qf[4];
    {
        const size_t rb = ((size_t)(b * 1024) + qb + wave * 16 + l16) * 6144 + h * 128;
        for (int kc = 0; kc < 4; kc++)
            qf[kc] = *(const bf16x8*)(QKV + rb + kc * 32 + quad * 8);
    }

    float m_i[4], l_i[4];
    floatx4 zero = {0.f, 0.f, 0.f, 0.f};
    floatx4 oacc[8];
    for (int r = 0; r < 4; r++) { m_i[r] = NEG_BIG; l_i[r] = 0.f; }
    for (int ni = 0; ni < 8; ni++) oacc[ni] = zero;

    const int ntiles = qb / 32 + 2;             // causal bound
    for (int tk = 0; tk < ntiles; ++tk) {
        const int kv0 = tk * 32;
        __syncthreads();
        // stage K tile: 32 rows x 128 elems = 512 x 16B chunks
        for (int j = 0; j < 2; j++) {
            const int chunk = (wave * 2 + j) * 64 + lane;
            const int row = chunk >> 4;
            const int kc  = chunk & 15;
            GLD16(QKV + ((size_t)(b * 1024) + kv0 + row) * 6144 + 2048 + h * 128 + kc * 8,
                  Kt + (wave * 2 + j) * 512);
        }
        // stage V tile: contiguous 8KB blob
        {
            const __hip_bfloat16* g = Vpt + ((((size_t)(b * 16 + h)) * 32) + tk) * 4096;
            for (int j = 0; j < 2; j++) {
                const int chunk = (wave * 2 + j) * 64 + lane;
                GLD16(g + chunk * 8, Vt + (wave * 2 + j) * 512);
            }
        }
        __syncthreads();

        // Sc = Q K^T  (2 col-blocks of 16, K=128 via 4 MFMAs)
        floatx4 sc[2];
        for (int cb = 0; cb < 2; cb++) {
            floatx4 s = zero;
            for (int kc = 0; kc < 4; kc++) {
                bf16x8 kf = *(const bf16x8*)(Kt + (cb * 16 + l16) * 128 + kc * 32 + quad * 8);
                s = __builtin_amdgcn_mfma_f32_16x16x32_bf16(qf[kc], kf, s, 0, 0, 0);
            }
            sc[cb] = s;
        }

        // scale + causal mask (finite sentinel)
        float tmax[4];
        for (int r = 0; r < 4; r++) {
            const int qrow = qb + wave * 16 + quad * 4 + r;
            for (int cb = 0; cb < 2; cb++) {
                const int col = kv0 + cb * 16 + l16;
                const float v = sc[cb][r] * scale;
                sc[cb][r] = (col > qrow) ? NEG_BIG : v;
            }
            tmax[r] = fmaxf(sc[0][r], sc[1][r]);
        }
        for (int off = 1; off < 16; off <<= 1)
            for (int r = 0; r < 4; r++)
                tmax[r] = fmaxf(tmax[r], __shfl_xor(tmax[r], off));

        float alpha[4], rsum[4];
        for (int r = 0; r < 4; r++) {
            const float mnew = fmaxf(m_i[r], tmax[r]);
            alpha[r] = __expf(m_i[r] - mnew);   // first tile: exp(-1e30) == 0
            const float p0 = __expf(sc[0][r] - mnew);
            const float p1 = __expf(sc[1][r] - mnew);
            sc[0][r] = p0; sc[1][r] = p1;
            rsum[r] = p0 + p1;
            m_i[r] = mnew;
        }
        for (int off = 1; off < 16; off <<= 1)
            for (int r = 0; r < 4; r++)
                rsum[r] += __shfl_xor(rsum[r], off);
        for (int r = 0; r < 4; r++) l_i[r] = l_i[r] * alpha[r] + rsum[r];
        for (int ni = 0; ni < 8; ni++)
            for (int r = 0; r < 4; r++) oacc[ni][r] *= alpha[r];

        // P -> LDS (C-layout write, A-layout read)
        for (int cb = 0; cb < 2; cb++)
            for (int r = 0; r < 4; r++)
                Pl[(wave * 16 + quad * 4 + r) * 32 + cb * 16 + l16] =
                    __float2bfloat16(sc[cb][r]);
        __syncthreads();

        // O += P V : A = P[16x32], B = V[32x128] (from Vt[hd][kv])
        bf16x8 pf = *(const bf16x8*)(Pl + (wave * 16 + l16) * 32 + quad * 8);
        for (int ni = 0; ni < 8; ni++) {
            bf16x8 vf = *(const bf16x8*)(Vt + (ni * 16 + l16) * 32 + quad * 8);
            oacc[ni] = __builtin_amdgcn_mfma_f32_16x16x32_bf16(pf, vf, oacc[ni], 0, 0, 0);
        }
    }

    // epilogue: O into QKV's V-columns (stride 6144, col offset 4096)
    for (int ni = 0; ni < 8; ni++) {
        for (int r = 0; r < 4; r++) {
            const int row = qb + wave * 16 + quad * 4 + r;
            const float v = oacc[ni][r] / l_i[r];
            O[((size_t)(b * 1024) + row) * 6144 + 4096 + h * 128 + ni * 16 + l16] =
                __float2bfloat16(v);
        }
    }
}

// ============================================================================
extern "C" void kernel_launch(void* const* d_in, const int* in_sizes, int n_in,
                              void* d_out, int out_size, void* d_ws, size_t ws_size,
                              hipStream_t stream) {
    const float* query = (const float*)d_in[0];
    // d_in[1] (key), d_in[2] (value) are ignored by the module
    const float* Wqkv = (const float*)d_in[3];
    const float* bqkv = (const float*)d_in[4];
    const float* Wout = (const float*)d_in[5];
    const float* bout = (const float*)d_in[6];
    float* out = (float*)d_out;   // reference output dtype is FLOAT32

    const size_t MB = 1048576;
    // ws layout:
    //   QKV bf16   48MB @0   (V cols become Att after flash)
    //   Vpt        16MB @48
    //   Qbf        16MB @64   (bf16 pre-converted query)
    //   Wqkv_bf    24MB @80
    //   Wout_bf     8MB @104  -> peak 112MB
    char* ws = (char*)d_ws;
    __hip_bfloat16* QKV = (__hip_bfloat16*)ws;
    __hip_bfloat16* Vpt = (__hip_bfloat16*)(ws + 48 * MB);
    __hip_bfloat16* Att = QKV + 4096;            // column offset, lda = 6144

    dim3 blk(256);

    if (ws_size >= 113 * MB) {
        // ---- bf16 pre-convert path (GLD16 staging in both GEMMs) ----
        __hip_bfloat16* Qbf     = (__hip_bfloat16*)(ws + 64 * MB);
        __hip_bfloat16* Wqkv_bf = (__hip_bfloat16*)(ws + 80 * MB);
        __hip_bfloat16* Wout_bf = (__hip_bfloat16*)(ws + 104 * MB);

        // 0) convert query / Wqkv / Wout to bf16 in one fused pass
        cvt3_f32_bf16<<<dim3(2048), blk, 0, stream>>>(
            query, (size_t)4096 * 2048 / 8,
            Wqkv,  (size_t)6144 * 2048 / 8,
            Wout,  (size_t)2048 * 2048 / 8,
            Qbf, Wqkv_bf, Wout_bf);
        // 1) QKV projection: bf16 x bf16 -> bf16
        gemm_nt_bias<false, false, false><<<dim3(48, 32), blk, 0, stream>>>(
            Qbf, Wqkv_bf, bqkv, QKV, 4096, 6144, 2048, 2048, 2048);
        // 2) V permutation -> blocked/transposed layout
        permute_v<<<dim3(2048), blk, 0, stream>>>(QKV, Vpt);
        // 3) causal flash attention (writes into QKV's dead V columns)
        flash_attn<<<dim3(16, 64), blk, 0, stream>>>(QKV, Vpt, QKV);
        // 4) out projection: bf16 x bf16 -> f32
        gemm_nt_bias<false, false, true><<<dim3(16, 32), blk, 0, stream>>>(
            Att, Wout_bf, bout, out, 4096, 2048, 2048, 6144, 2048);
    } else {
        // ---- fallback: fused-convert path (64MB workspace) ----
        gemm_nt_bias<true, true, false><<<dim3(48, 32), blk, 0, stream>>>(
            query, Wqkv, bqkv, QKV, 4096, 6144, 2048, 2048, 2048);
        permute_v<<<dim3(2048), blk, 0, stream>>>(QKV, Vpt);
        flash_attn<<<dim3(16, 64), blk, 0, stream>>>(QKV, Vpt, QKV);
        gemm_nt_bias<false, true, true><<<dim3(16, 32), blk, 0, stream>>>(
            Att, Wout, bout, out, 4096, 2048, 2048, 6144, 2048);
    }
}

// Round 2
// 390.363 us; speedup vs baseline: 1.4990x; 1.2299x over previous
//
#include <hip/hip_runtime.h>
#include <hip/hip_bf16.h>
#include <stdint.h>

// ---- types ----
typedef __bf16 bf16x8 __attribute__((ext_vector_type(8)));
typedef float  floatx4 __attribute__((ext_vector_type(4)));

#define NEG_BIG (-1e30f)   // finite sentinel: exp(NEG_BIG - m) == 0

// async global->LDS, 16B per lane; LDS dest = wave-uniform base + lane*16
#define GLD16(g, l) __builtin_amdgcn_global_load_lds(                         \
    (__attribute__((address_space(1))) void*)(g),                             \
    (__attribute__((address_space(3))) void*)(l), 16, 0, 0)

// convert 16 fp32 -> 16 bf16, store 32B to LDS
__device__ __forceinline__ void cvt16(const float* __restrict__ s,
                                      __hip_bfloat16* __restrict__ d) {
    float4 f[4];
#pragma unroll
    for (int i = 0; i < 4; i++) f[i] = ((const float4*)s)[i];
    union { __hip_bfloat16 h[16]; uint4 u[2]; } o;
#pragma unroll
    for (int i = 0; i < 4; i++) {
        o.h[4 * i + 0] = __float2bfloat16(f[i].x);
        o.h[4 * i + 1] = __float2bfloat16(f[i].y);
        o.h[4 * i + 2] = __float2bfloat16(f[i].z);
        o.h[4 * i + 3] = __float2bfloat16(f[i].w);
    }
    ((uint4*)d)[0] = o.u[0];
    ((uint4*)d)[1] = o.u[1];
}

// ============================================================================
// Fused fp32->bf16 convert of up to 3 arrays (grid-stride, 8 elems/thread).
// ============================================================================
__global__ __launch_bounds__(256)
void cvt3_f32_bf16(const float* __restrict__ a, size_t na8,
                   const float* __restrict__ b, size_t nb8,
                   const float* __restrict__ c, size_t nc8,
                   __hip_bfloat16* __restrict__ da,
                   __hip_bfloat16* __restrict__ db,
                   __hip_bfloat16* __restrict__ dc)
{
    const size_t total  = na8 + nb8 + nc8;
    const size_t stride = (size_t)gridDim.x * blockDim.x;
    for (size_t idx = (size_t)blockIdx.x * blockDim.x + threadIdx.x;
         idx < total; idx += stride) {
        const float* s; __hip_bfloat16* d; size_t o;
        if (idx < na8)            { s = a; d = da; o = idx; }
        else if (idx < na8 + nb8) { s = b; d = db; o = idx - na8; }
        else                      { s = c; d = dc; o = idx - na8 - nb8; }
        const float4 f0 = ((const float4*)s)[o * 2 + 0];
        const float4 f1 = ((const float4*)s)[o * 2 + 1];
        union { __hip_bfloat16 h[8]; uint4 u; } z;
        z.h[0] = __float2bfloat16(f0.x); z.h[1] = __float2bfloat16(f0.y);
        z.h[2] = __float2bfloat16(f0.z); z.h[3] = __float2bfloat16(f0.w);
        z.h[4] = __float2bfloat16(f1.x); z.h[5] = __float2bfloat16(f1.y);
        z.h[6] = __float2bfloat16(f1.z); z.h[7] = __float2bfloat16(f1.w);
        ((uint4*)d)[o] = z.u;
    }
}

// ============================================================================
// NT GEMM: C[M,N] = A[M,K] * B[N,K]^T + bias[N].  (unchanged from prev round)
// ============================================================================
template <bool A_F32, bool B_F32, bool OUT_F32>
__global__ __launch_bounds__(256, 2)
void gemm_nt_bias(const void* __restrict__ Av, const void* __restrict__ Bv,
                  const float* __restrict__ bias, void* __restrict__ Cv,
                  int M, int N, int K, int lda, int ldb)
{
    __shared__ __align__(16) __hip_bfloat16 Asm[128 * 32];
    __shared__ __align__(16) __hip_bfloat16 Bsm[128 * 32];
    const int m0   = blockIdx.y * 128;
    const int n0   = blockIdx.x * 128;
    const int t    = threadIdx.x;
    const int wave = t >> 6, lane = t & 63;
    const int quad = lane >> 4, l16 = lane & 15;
    const int wr   = wave >> 1, wc = wave & 1;

    floatx4 zero = {0.f, 0.f, 0.f, 0.f};
    floatx4 acc[4][4];
    for (int i = 0; i < 4; i++)
        for (int j = 0; j < 4; j++) acc[i][j] = zero;

    for (int k0 = 0; k0 < K; k0 += 32) {
        if (A_F32) {
            const float* A = (const float*)Av;
            const int row = t >> 1, half = t & 1;
            cvt16(A + (size_t)(m0 + row) * lda + k0 + half * 16,
                  Asm + row * 32 + half * 16);
        } else {
            const __hip_bfloat16* A = (const __hip_bfloat16*)Av;
            for (int j = 0; j < 2; ++j) {
                const int chunk = (wave * 2 + j) * 64 + lane;
                const int row   = chunk >> 2;
                const int kc    = chunk & 3;
                GLD16(A + (size_t)(m0 + row) * lda + k0 + kc * 8,
                      Asm + (wave * 2 + j) * 512);
            }
        }
        if (B_F32) {
            const float* B = (const float*)Bv;
            const int row = t >> 1, half = t & 1;
            cvt16(B + (size_t)(n0 + row) * ldb + k0 + half * 16,
                  Bsm + row * 32 + half * 16);
        } else {
            const __hip_bfloat16* B = (const __hip_bfloat16*)Bv;
            for (int j = 0; j < 2; ++j) {
                const int chunk = (wave * 2 + j) * 64 + lane;
                const int row   = chunk >> 2;
                const int kc    = chunk & 3;
                GLD16(B + (size_t)(n0 + row) * ldb + k0 + kc * 8,
                      Bsm + (wave * 2 + j) * 512);
            }
        }
        __syncthreads();

        bf16x8 af[4], bf[4];
        for (int i = 0; i < 4; i++) {
            af[i] = *(const bf16x8*)(Asm + (wr * 64 + i * 16 + l16) * 32 + quad * 8);
            bf[i] = *(const bf16x8*)(Bsm + (wc * 64 + i * 16 + l16) * 32 + quad * 8);
        }
        for (int mi = 0; mi < 4; mi++)
            for (int ni = 0; ni < 4; ni++)
                acc[mi][ni] = __builtin_amdgcn_mfma_f32_16x16x32_bf16(
                    af[mi], bf[ni], acc[mi][ni], 0, 0, 0);
        __syncthreads();
    }

    for (int mi = 0; mi < 4; mi++) {
        const int row = m0 + wr * 64 + mi * 16 + quad * 4;
        for (int ni = 0; ni < 4; ni++) {
            const int col = n0 + wc * 64 + ni * 16 + l16;
            const float bv = bias[col];
            for (int r = 0; r < 4; r++) {
                const float v = acc[mi][ni][r] + bv;
                if (OUT_F32)
                    ((float*)Cv)[(size_t)(row + r) * N + col] = v;
                else
                    ((__hip_bfloat16*)Cv)[(size_t)(row + r) * N + col] =
                        __float2bfloat16(v);
            }
        }
    }
}

// ============================================================================
// V permutation (unchanged): Vpt[b][h][sb32][hd][ss32], 8KB blobs.
// ============================================================================
__global__ __launch_bounds__(256)
void permute_v(const __hip_bfloat16* __restrict__ QKV,
               __hip_bfloat16* __restrict__ Vpt)
{
    __shared__ __align__(16) __hip_bfloat16 S[64 * 64];
    const int blk = blockIdx.x;
    const int sb = blk & 31, h = (blk >> 5) & 15, b = blk >> 9;
    const int t = threadIdx.x;

    for (int j = 0; j < 2; j++) {
        const int chunk = j * 256 + t;
        const int lrow  = chunk >> 3;
        const int lcol  = (chunk & 7) * 8;
        const int r8 = lrow >> 3, jj = lrow & 7;
        const int srow = r8 * 128 + h * 8 + jj;
        const int scol = sb * 64 + lcol;
        *(uint4*)(S + chunk * 8) =
            *(const uint4*)(QKV + ((size_t)(b * 1024) + srow) * 6144 + 4096 + scol);
    }
    __syncthreads();

    const size_t obase = (((size_t)(b * 16 + h)) * 32 + sb) * 4096;
    for (int i = 0; i < 16; i++) {
        const int lin = t + 256 * i;
        const int hd = lin >> 5, ss = lin & 31;
        Vpt[obase + lin] =
            S[((ss & 7) * 8 + (hd >> 4)) * 64 + (ss >> 3) * 16 + (hd & 15)];
    }
}

// ============================================================================
// Causal flash attention v2.
//  - QBLK=64 (4 waves x 16 rows), KVBLK=64, double-buffered K/V in LDS.
//  - Counted vmcnt(8): next tile's 8 global_load_lds stay in flight across
//    raw s_barrier (no __syncthreads drain in the main loop).
//  - Paired q-tiles (p and 15-p) -> uniform 17 kv-tiles per block; 512 blocks
//    = exactly 2/CU; bid = pair*64 + bh so blocks sharing (b,h) share an XCD.
//  - XOR swizzle (granule ^= row&7) on K and P: pre-swizzled GLD16 source +
//    swizzled reads (same involution both sides). V (32-wide blobs) uses a
//    2-bit swizzle -> 4-way residual.
//  - P tile written & read by the same wave: lgkmcnt(0), no barrier.
// ============================================================================
__global__ __launch_bounds__(256, 2)
void flash_attn(const __hip_bfloat16* __restrict__ QKV,
                const __hip_bfloat16* __restrict__ Vpt,
                __hip_bfloat16* __restrict__ O)   // == QKV buffer
{
    __shared__ __align__(16) __hip_bfloat16 Kt[2][64 * 128];   // [buf][kv][hd] swz
    __shared__ __align__(16) __hip_bfloat16 Vt[2][2 * 128 * 32]; // [buf][half][hd][kv32] swz
    __shared__ __align__(16) __hip_bfloat16 Pl[64 * 64];       // [qrow][kv] swz

    const int bid  = blockIdx.x;
    const int pair = bid >> 6;               // 0..7
    const int g    = bid & 63;               // bh group; g&7 keeps bh on one XCD
    const int b    = g >> 4, h = g & 15;
    const int t    = threadIdx.x;
    const int wave = t >> 6, lane = t & 63;
    const int quad = lane >> 4, l16 = lane & 15;
    const float scale = 0.08838834764831845f;   // 128^-0.5

    const int    rowb  = b * 1024;
    const size_t vbase = (((size_t)(b * 16 + h)) * 32) * 4096;
    const floatx4 zero = {0.f, 0.f, 0.f, 0.f};

    // ---- staging helpers (8 GLD16 per thread per tile total) ----
    auto stageK = [&](int tk, int bufi) {
        const int kv0 = tk * 64;
        __hip_bfloat16* dst = &Kt[bufi][0];
#pragma unroll
        for (int j = 0; j < 4; j++) {
            const int c0 = (wave * 4 + j) * 64 + lane;   // 0..1023
            const int r  = c0 >> 4;                      // kv row 0..63
            const int gg = (c0 & 15) ^ (r & 7);          // pre-swizzled src granule
            GLD16(QKV + ((size_t)(rowb + kv0 + r)) * 6144 + 2048 + h * 128 + gg * 8,
                  dst + (wave * 4 + j) * 512);
        }
    };
    auto stageV = [&](int tk, int bufi) {
        const __hip_bfloat16* src = Vpt + vbase + (size_t)(tk * 2) * 4096;
        __hip_bfloat16* dst = &Vt[bufi][0];
#pragma unroll
        for (int j = 0; j < 4; j++) {
            const int c0   = (wave * 4 + j) * 64 + lane; // 0..1023
            const int half = c0 >> 9, w = c0 & 511;
            const int r    = w >> 2;                     // hd row 0..127
            const int gg   = (w & 3) ^ (r & 3);          // 2-bit swizzle
            GLD16(src + half * 4096 + r * 32 + gg * 8,
                  dst + (wave * 4 + j) * 512);
        }
    };

    for (int ph = 0; ph < 2; ++ph) {
        const int qb = ph ? (15 - pair) * 64 : pair * 64;
        const int nt = ph ? 16 - pair       : pair + 1;

        // Q fragments (A-layout: row=l16, k=quad*8+j)
        bf16x8 qf[4];
        {
            const size_t rb = ((size_t)(rowb + qb + wave * 16 + l16)) * 6144 + h * 128;
#pragma unroll
            for (int kc = 0; kc < 4; kc++)
                qf[kc] = *(const bf16x8*)(QKV + rb + kc * 32 + quad * 8);
        }

        float m_i[4], l_i[4];
        floatx4 oacc[8];
#pragma unroll
        for (int r = 0; r < 4; r++) { m_i[r] = NEG_BIG; l_i[r] = 0.f; }
#pragma unroll
        for (int ni = 0; ni < 8; ni++) oacc[ni] = zero;

        // prologue: stage tile 0
        stageK(0, 0); stageV(0, 0);

        for (int tk = 0; tk < nt; ++tk) {
            const int cur = tk & 1;
            if (tk + 1 < nt) {
                stageK(tk + 1, cur ^ 1); stageV(tk + 1, cur ^ 1);
                asm volatile("s_waitcnt vmcnt(8)" ::: "memory");  // cur tile done
            } else {
                asm volatile("s_waitcnt vmcnt(0)" ::: "memory");
            }
            __builtin_amdgcn_s_barrier();
            asm volatile("" ::: "memory");

            const __hip_bfloat16* Kb = &Kt[cur][0];
            const __hip_bfloat16* Vb = &Vt[cur][0];
            const int kv0 = tk * 64;

            // ---- Sc = Q K^T : 4 col-blocks x (K=128 via 4 MFMAs) ----
            floatx4 sc[4];
#pragma unroll
            for (int cb = 0; cb < 4; cb++) {
                floatx4 s = zero;
                const int r  = cb * 16 + l16;
                const int sw = r & 7;
#pragma unroll
                for (int kc = 0; kc < 4; kc++) {
                    bf16x8 kf = *(const bf16x8*)(
                        Kb + r * 128 + (((kc * 4 + quad) ^ sw) << 3));
                    s = __builtin_amdgcn_mfma_f32_16x16x32_bf16(qf[kc], kf, s, 0, 0, 0);
                }
                sc[cb] = s;
            }

            // ---- softmax (rows quad*4+rr, cols kv0 + cb*16 + l16) ----
            const int qrow = qb + wave * 16 + quad * 4;
            if (tk == nt - 1) {               // diagonal tile: mask
#pragma unroll
                for (int rr = 0; rr < 4; rr++)
#pragma unroll
                    for (int cb = 0; cb < 4; cb++) {
                        const int col = kv0 + cb * 16 + l16;
                        const float v = sc[cb][rr] * scale;
                        sc[cb][rr] = (col > qrow + rr) ? NEG_BIG : v;
                    }
            } else {
#pragma unroll
                for (int rr = 0; rr < 4; rr++)
#pragma unroll
                    for (int cb = 0; cb < 4; cb++) sc[cb][rr] *= scale;
            }
            float mx[4];
#pragma unroll
            for (int rr = 0; rr < 4; rr++)
                mx[rr] = fmaxf(fmaxf(sc[0][rr], sc[1][rr]),
                               fmaxf(sc[2][rr], sc[3][rr]));
#pragma unroll
            for (int off = 1; off < 16; off <<= 1)
#pragma unroll
                for (int rr = 0; rr < 4; rr++)
                    mx[rr] = fmaxf(mx[rr], __shfl_xor(mx[rr], off));

            float alpha[4], rsum[4];
#pragma unroll
            for (int rr = 0; rr < 4; rr++) {
                const float mnew = fmaxf(m_i[rr], mx[rr]);
                alpha[rr] = __expf(m_i[rr] - mnew);
                m_i[rr] = mnew;
                float acc = 0.f;
#pragma unroll
                for (int cb = 0; cb < 4; cb++) {
                    const float pv = __expf(sc[cb][rr] - mnew);
                    sc[cb][rr] = pv;
                    acc += pv;
                }
                rsum[rr] = acc;
            }
#pragma unroll
            for (int off = 1; off < 16; off <<= 1)
#pragma unroll
                for (int rr = 0; rr < 4; rr++)
                    rsum[rr] += __shfl_xor(rsum[rr], off);
#pragma unroll
            for (int rr = 0; rr < 4; rr++)
                l_i[rr] = l_i[rr] * alpha[rr] + rsum[rr];
#pragma unroll
            for (int ni = 0; ni < 8; ni++)
#pragma unroll
                for (int rr = 0; rr < 4; rr++) oacc[ni][rr] *= alpha[rr];

            // ---- P -> LDS (swizzled; same-wave produce/consume) ----
#pragma unroll
            for (int cb = 0; cb < 4; cb++)
#pragma unroll
                for (int rr = 0; rr < 4; rr++) {
                    const int row = wave * 16 + quad * 4 + rr;
                    const int col = cb * 16 + l16;
                    Pl[row * 64 + ((((col >> 3) ^ (row & 7)) << 3) | (col & 7))] =
                        __float2bfloat16(sc[cb][rr]);
                }
            asm volatile("s_waitcnt lgkmcnt(0)" ::: "memory");

            // ---- O += P V ----
            const int prow = wave * 16 + l16;
            bf16x8 pf[2];
#pragma unroll
            for (int kc = 0; kc < 2; kc++)
                pf[kc] = *(const bf16x8*)(
                    Pl + prow * 64 + (((kc * 4 + quad) ^ (prow & 7)) << 3));
#pragma unroll
            for (int ni = 0; ni < 8; ni++) {
                const int vr = ni * 16 + l16;
#pragma unroll
                for (int kc = 0; kc < 2; kc++) {
                    bf16x8 vf = *(const bf16x8*)(
                        Vb + kc * 4096 + vr * 32 + (((quad ^ (vr & 3))) << 3));
                    oacc[ni] = __builtin_amdgcn_mfma_f32_16x16x32_bf16(
                        pf[kc], vf, oacc[ni], 0, 0, 0);
                }
            }

            asm volatile("" ::: "memory");
            __builtin_amdgcn_s_barrier();   // all waves done with buf[cur]
            asm volatile("" ::: "memory");
        }

        // ---- epilogue: O into QKV's dead V-columns ----
        float inv[4];
#pragma unroll
        for (int rr = 0; rr < 4; rr++) inv[rr] = 1.0f / l_i[rr];
#pragma unroll
        for (int ni = 0; ni < 8; ni++)
#pragma unroll
            for (int rr = 0; rr < 4; rr++) {
                const int row = qb + wave * 16 + quad * 4 + rr;
                O[((size_t)rowb + row) * 6144 + 4096 + h * 128 + ni * 16 + l16] =
                    __float2bfloat16(oacc[ni][rr] * inv[rr]);
            }
    }
}

// ============================================================================
extern "C" void kernel_launch(void* const* d_in, const int* in_sizes, int n_in,
                              void* d_out, int out_size, void* d_ws, size_t ws_size,
                              hipStream_t stream) {
    const float* query = (const float*)d_in[0];
    const float* Wqkv = (const float*)d_in[3];
    const float* bqkv = (const float*)d_in[4];
    const float* Wout = (const float*)d_in[5];
    const float* bout = (const float*)d_in[6];
    float* out = (float*)d_out;

    const size_t MB = 1048576;
    char* ws = (char*)d_ws;
    __hip_bfloat16* QKV = (__hip_bfloat16*)ws;
    __hip_bfloat16* Vpt = (__hip_bfloat16*)(ws + 48 * MB);
    __hip_bfloat16* Att = QKV + 4096;            // column offset, lda = 6144

    dim3 blk(256);

    if (ws_size >= 113 * MB) {
        __hip_bfloat16* Qbf     = (__hip_bfloat16*)(ws + 64 * MB);
        __hip_bfloat16* Wqkv_bf = (__hip_bfloat16*)(ws + 80 * MB);
        __hip_bfloat16* Wout_bf = (__hip_bfloat16*)(ws + 104 * MB);

        cvt3_f32_bf16<<<dim3(2048), blk, 0, stream>>>(
            query, (size_t)4096 * 2048 / 8,
            Wqkv,  (size_t)6144 * 2048 / 8,
            Wout,  (size_t)2048 * 2048 / 8,
            Qbf, Wqkv_bf, Wout_bf);
        gemm_nt_bias<false, false, false><<<dim3(48, 32), blk, 0, stream>>>(
            Qbf, Wqkv_bf, bqkv, QKV, 4096, 6144, 2048, 2048, 2048);
        permute_v<<<dim3(2048), blk, 0, stream>>>(QKV, Vpt);
        flash_attn<<<dim3(512), blk, 0, stream>>>(QKV, Vpt, QKV);
        gemm_nt_bias<false, false, true><<<dim3(16, 32), blk, 0, stream>>>(
            Att, Wout_bf, bout, out, 4096, 2048, 2048, 6144, 2048);
    } else {
        gemm_nt_bias<true, true, false><<<dim3(48, 32), blk, 0, stream>>>(
            query, Wqkv, bqkv, QKV, 4096, 6144, 2048, 2048, 2048);
        permute_v<<<dim3(2048), blk, 0, stream>>>(QKV, Vpt);
        flash_attn<<<dim3(512), blk, 0, stream>>>(QKV, Vpt, QKV);
        gemm_nt_bias<false, true, true><<<dim3(16, 32), blk, 0, stream>>>(
            Att, Wout, bout, out, 4096, 2048, 2048, 6144, 2048);
    }
}

// Round 3
// 388.582 us; speedup vs baseline: 1.5058x; 1.0046x over previous
//
#include <hip/hip_runtime.h>
#include <hip/hip_bf16.h>
#include <stdint.h>

// ---- types ----
typedef __bf16 bf16x8 __attribute__((ext_vector_type(8)));
typedef float  floatx4 __attribute__((ext_vector_type(4)));

#define NEG_BIG (-1e30f)   // finite sentinel: exp(NEG_BIG - m) == 0

// async global->LDS, 16B per lane; LDS dest = wave-uniform base + lane*16
#define GLD16(g, l) __builtin_amdgcn_global_load_lds(                         \
    (__attribute__((address_space(1))) void*)(g),                             \
    (__attribute__((address_space(3))) void*)(l), 16, 0, 0)

// convert 16 fp32 -> 16 bf16, store 32B to LDS
__device__ __forceinline__ void cvt16(const float* __restrict__ s,
                                      __hip_bfloat16* __restrict__ d) {
    float4 f[4];
#pragma unroll
    for (int i = 0; i < 4; i++) f[i] = ((const float4*)s)[i];
    union { __hip_bfloat16 h[16]; uint4 u[2]; } o;
#pragma unroll
    for (int i = 0; i < 4; i++) {
        o.h[4 * i + 0] = __float2bfloat16(f[i].x);
        o.h[4 * i + 1] = __float2bfloat16(f[i].y);
        o.h[4 * i + 2] = __float2bfloat16(f[i].z);
        o.h[4 * i + 3] = __float2bfloat16(f[i].w);
    }
    ((uint4*)d)[0] = o.u[0];
    ((uint4*)d)[1] = o.u[1];
}

// ============================================================================
// Fused fp32->bf16 convert of up to 3 arrays (grid-stride, 8 elems/thread).
// ============================================================================
__global__ __launch_bounds__(256)
void cvt3_f32_bf16(const float* __restrict__ a, size_t na8,
                   const float* __restrict__ b, size_t nb8,
                   const float* __restrict__ c, size_t nc8,
                   __hip_bfloat16* __restrict__ da,
                   __hip_bfloat16* __restrict__ db,
                   __hip_bfloat16* __restrict__ dc)
{
    const size_t total  = na8 + nb8 + nc8;
    const size_t stride = (size_t)gridDim.x * blockDim.x;
    for (size_t idx = (size_t)blockIdx.x * blockDim.x + threadIdx.x;
         idx < total; idx += stride) {
        const float* s; __hip_bfloat16* d; size_t o;
        if (idx < na8)            { s = a; d = da; o = idx; }
        else if (idx < na8 + nb8) { s = b; d = db; o = idx - na8; }
        else                      { s = c; d = dc; o = idx - na8 - nb8; }
        const float4 f0 = ((const float4*)s)[o * 2 + 0];
        const float4 f1 = ((const float4*)s)[o * 2 + 1];
        union { __hip_bfloat16 h[8]; uint4 u; } z;
        z.h[0] = __float2bfloat16(f0.x); z.h[1] = __float2bfloat16(f0.y);
        z.h[2] = __float2bfloat16(f0.z); z.h[3] = __float2bfloat16(f0.w);
        z.h[4] = __float2bfloat16(f1.x); z.h[5] = __float2bfloat16(f1.y);
        z.h[6] = __float2bfloat16(f1.z); z.h[7] = __float2bfloat16(f1.w);
        ((uint4*)d)[o] = z.u;
    }
}

// ============================================================================
// 256x256 8-phase NT GEMM (T2+T3+T4+T5 port): C[M,N] = A[M,K]*B[N,K]^T + bias.
// bf16 in, bf16/f32 out. 512 threads = 8 waves (2M x 4N), per-wave 128x64 out.
// BK=64; LDS = 2buf x (A 32KB + B 32KB) = 128KB. Requires M%256==0, N%256==0,
// K%64==0, grid%8==0 (XCD swizzle).
//
// Phase p of tile t: {ds_read A-quad (+B all, p0 only, held in regs) |
//   issue 1 half-stage of future tile | barrier | lgkmcnt(0) | setprio(1) |
//   16 MFMA | setprio(0) | [p3: vmcnt(3)] | barrier}.
// Staging skew (race-free: A stripe-band b of tile t is dead after phase b;
// B of tile t dead after phase 0):
//   p0: Aband3(t+1), Bh0(t+1)   [buf^1]
//   p1: Bh1(t+1) [buf^1];  Aband0(t+2) [cur buf, overwrites dead band0(t)]
//   p2: Aband1(t+2)             p3: Aband2(t+2)
// At tile end, the 3 youngest loads are Abands0-2(t+2) -> vmcnt(3) ensures
// tile t+1 fully resident without ever draining the queue.
// A stripe-band b = rows [32b,32b+32) U [128+32b,128+32b+32)  (matches the
// per-phase consumption rows wr*128 + {2p,2p+1}*16).
// XOR swizzle: LDS granule(16B) = src_granule ^ (row&7), applied on GLD16
// source and ds_read address (same involution both sides).
// ============================================================================
template <bool OUT_F32>
__global__ __launch_bounds__(512, 2)
void gemm256_nt_bias(const __hip_bfloat16* __restrict__ A,
                     const __hip_bfloat16* __restrict__ B,
                     const float* __restrict__ bias, void* __restrict__ Cv,
                     int M, int N, int K, int lda, int ldb, int nbx)
{
    __shared__ __align__(16) __hip_bfloat16 Asm[2][256 * 64];
    __shared__ __align__(16) __hip_bfloat16 Bsm[2][256 * 64];

    // XCD swizzle (grid multiple of 8)
    const int nwg = gridDim.x, cpx = nwg >> 3;
    const int flat = blockIdx.x;
    const int swz  = (flat & 7) * cpx + (flat >> 3);
    const int bx = swz % nbx, by = swz / nbx;
    const int m0 = by * 256, n0 = bx * 256;

    const int t    = threadIdx.x;
    const int wave = t >> 6, lane = t & 63;
    const int quad = lane >> 4, l16 = lane & 15;
    const int wr   = wave >> 2, wc = wave & 3;
    const int NT   = K >> 6;

    // ---- staging geometry ----
    const int s_   = wave >> 2;              // A stripe (0/1)
    const int w3   = wave & 3;
    const int l8   = lane >> 3;              // 0..7
    const int g_   = (lane & 7) ^ l8;        // pre-swizzled source granule
    // A: thread covers row  s_*128 + b*32 + w3*8 + l8  (b = band)
    const __hip_bfloat16* aSrc = A + (size_t)(m0 + s_ * 128 + w3 * 8 + l8) * lda + g_ * 8;
    // B: thread covers row  h*128 + j*64 + wave*8 + l8
    const __hip_bfloat16* bSrc = B + (size_t)(n0 + wave * 8 + l8) * ldb + g_ * 8;

    auto stageA = [&](int tk, int b, int buf) {
        GLD16(aSrc + (size_t)(b * 32) * lda + tk * 64,
              &Asm[buf][0] + (s_ * 128 + b * 32 + w3 * 8) * 64);
    };
    auto stageBhalf = [&](int tk, int h, int buf) {
#pragma unroll
        for (int j = 0; j < 2; j++)
            GLD16(bSrc + (size_t)(h * 128 + j * 64) * ldb + tk * 64,
                  &Bsm[buf][0] + (h * 128 + j * 64 + wave * 8) * 64);
    };

    // ds_read granule base (swizzled): row&7 == l16&7 for all frag rows
    const int g0 = (quad ^ (l16 & 7)) << 3;   // bf16 offset; ks flips +32 (XOR)

    floatx4 acc[8][4];
    const floatx4 zero = {0.f, 0.f, 0.f, 0.f};
#pragma unroll
    for (int mi = 0; mi < 8; mi++)
#pragma unroll
        for (int ni = 0; ni < 4; ni++) acc[mi][ni] = zero;

    // ---- prologue ----
    stageA(0, 0, 0); stageA(0, 1, 0); stageA(0, 2, 0); stageA(0, 3, 0);
    stageBhalf(0, 0, 0); stageBhalf(0, 1, 0);
    if (NT > 1) {
        stageA(1, 0, 1); stageA(1, 1, 1); stageA(1, 2, 1);
        asm volatile("s_waitcnt vmcnt(3)" ::: "memory");
    } else {
        asm volatile("s_waitcnt vmcnt(0)" ::: "memory");
    }
    __syncthreads();

    bf16x8 bfr[4][2];
    int cb = 0;
    for (int tk = 0; tk < NT; ++tk, cb ^= 1) {
        const __hip_bfloat16* Ab = &Asm[cb][0];
        const __hip_bfloat16* Bb = &Bsm[cb][0];
        const int nb = cb ^ 1;

#pragma unroll
        for (int p = 0; p < 4; p++) {
            // ---- ds reads for this phase ----
            bf16x8 af[2][2];
#pragma unroll
            for (int i = 0; i < 2; i++)
#pragma unroll
                for (int ks = 0; ks < 2; ks++)
                    af[i][ks] = *(const bf16x8*)(
                        Ab + (wr * 128 + (2 * p + i) * 16 + l16) * 64 +
                        (g0 ^ (ks ? 32 : 0)));
            if (p == 0) {
#pragma unroll
                for (int ni = 0; ni < 4; ni++)
#pragma unroll
                    for (int ks = 0; ks < 2; ks++)
                        bfr[ni][ks] = *(const bf16x8*)(
                            Bb + (wc * 64 + ni * 16 + l16) * 64 +
                            (g0 ^ (ks ? 32 : 0)));
            }
            // ---- staging (skewed; see header comment) ----
            if (p == 0) {
                if (tk + 1 < NT) { stageA(tk + 1, 3, nb); stageBhalf(tk + 1, 0, nb); }
            } else if (p == 1) {
                if (tk + 1 < NT) stageBhalf(tk + 1, 1, nb);
                if (tk + 2 < NT) stageA(tk + 2, 0, cb);
            } else if (p == 2) {
                if (tk + 2 < NT) stageA(tk + 2, 1, cb);
            } else {
                if (tk + 2 < NT) stageA(tk + 2, 2, cb);
            }

            __builtin_amdgcn_s_barrier();
            asm volatile("s_waitcnt lgkmcnt(0)" ::: "memory");
            __builtin_amdgcn_s_setprio(1);
#pragma unroll
            for (int ks = 0; ks < 2; ks++)
#pragma unroll
                for (int i = 0; i < 2; i++)
#pragma unroll
                    for (int ni = 0; ni < 4; ni++)
                        acc[2 * p + i][ni] = __builtin_amdgcn_mfma_f32_16x16x32_bf16(
                            af[i][ks], bfr[ni][ks], acc[2 * p + i][ni], 0, 0, 0);
            __builtin_amdgcn_s_setprio(0);
            if (p == 3) {
                if (tk + 2 < NT)
                    asm volatile("s_waitcnt vmcnt(3)" ::: "memory");
                else if (tk + 1 < NT)
                    asm volatile("s_waitcnt vmcnt(0)" ::: "memory");
            }
            __builtin_amdgcn_s_barrier();
        }
    }

    // ---- epilogue ----
#pragma unroll
    for (int mi = 0; mi < 8; mi++) {
        const int row = m0 + wr * 128 + mi * 16 + quad * 4;
#pragma unroll
        for (int ni = 0; ni < 4; ni++) {
            const int col = n0 + wc * 64 + ni * 16 + l16;
            const float bv = bias[col];
#pragma unroll
            for (int r = 0; r < 4; r++) {
                const float v = acc[mi][ni][r] + bv;
                if (OUT_F32)
                    ((float*)Cv)[(size_t)(row + r) * N + col] = v;
                else
                    ((__hip_bfloat16*)Cv)[(size_t)(row + r) * N + col] =
                        __float2bfloat16(v);
            }
        }
    }
}

// ============================================================================
// 128x128 NT GEMM (m97 structure) — kept for out-proj (grid 512 = 2/CU) and
// the fp32 fallback path.
// ============================================================================
template <bool A_F32, bool B_F32, bool OUT_F32>
__global__ __launch_bounds__(256, 2)
void gemm_nt_bias(const void* __restrict__ Av, const void* __restrict__ Bv,
                  const float* __restrict__ bias, void* __restrict__ Cv,
                  int M, int N, int K, int lda, int ldb)
{
    __shared__ __align__(16) __hip_bfloat16 Asm[128 * 32];
    __shared__ __align__(16) __hip_bfloat16 Bsm[128 * 32];
    const int m0   = blockIdx.y * 128;
    const int n0   = blockIdx.x * 128;
    const int t    = threadIdx.x;
    const int wave = t >> 6, lane = t & 63;
    const int quad = lane >> 4, l16 = lane & 15;
    const int wr   = wave >> 1, wc = wave & 1;

    floatx4 zero = {0.f, 0.f, 0.f, 0.f};
    floatx4 acc[4][4];
    for (int i = 0; i < 4; i++)
        for (int j = 0; j < 4; j++) acc[i][j] = zero;

    for (int k0 = 0; k0 < K; k0 += 32) {
        if (A_F32) {
            const float* A = (const float*)Av;
            const int row = t >> 1, half = t & 1;
            cvt16(A + (size_t)(m0 + row) * lda + k0 + half * 16,
                  Asm + row * 32 + half * 16);
        } else {
            const __hip_bfloat16* A = (const __hip_bfloat16*)Av;
            for (int j = 0; j < 2; ++j) {
                const int chunk = (wave * 2 + j) * 64 + lane;
                const int row   = chunk >> 2;
                const int kc    = chunk & 3;
                GLD16(A + (size_t)(m0 + row) * lda + k0 + kc * 8,
                      Asm + (wave * 2 + j) * 512);
            }
        }
        if (B_F32) {
            const float* B = (const float*)Bv;
            const int row = t >> 1, half = t & 1;
            cvt16(B + (size_t)(n0 + row) * ldb + k0 + half * 16,
                  Bsm + row * 32 + half * 16);
        } else {
            const __hip_bfloat16* B = (const __hip_bfloat16*)Bv;
            for (int j = 0; j < 2; ++j) {
                const int chunk = (wave * 2 + j) * 64 + lane;
                const int row   = chunk >> 2;
                const int kc    = chunk & 3;
                GLD16(B + (size_t)(n0 + row) * ldb + k0 + kc * 8,
                      Bsm + (wave * 2 + j) * 512);
            }
        }
        __syncthreads();

        bf16x8 af[4], bf[4];
        for (int i = 0; i < 4; i++) {
            af[i] = *(const bf16x8*)(Asm + (wr * 64 + i * 16 + l16) * 32 + quad * 8);
            bf[i] = *(const bf16x8*)(Bsm + (wc * 64 + i * 16 + l16) * 32 + quad * 8);
        }
        for (int mi = 0; mi < 4; mi++)
            for (int ni = 0; ni < 4; ni++)
                acc[mi][ni] = __builtin_amdgcn_mfma_f32_16x16x32_bf16(
                    af[mi], bf[ni], acc[mi][ni], 0, 0, 0);
        __syncthreads();
    }

    for (int mi = 0; mi < 4; mi++) {
        const int row = m0 + wr * 64 + mi * 16 + quad * 4;
        for (int ni = 0; ni < 4; ni++) {
            const int col = n0 + wc * 64 + ni * 16 + l16;
            const float bv = bias[col];
            for (int r = 0; r < 4; r++) {
                const float v = acc[mi][ni][r] + bv;
                if (OUT_F32)
                    ((float*)Cv)[(size_t)(row + r) * N + col] = v;
                else
                    ((__hip_bfloat16*)Cv)[(size_t)(row + r) * N + col] =
                        __float2bfloat16(v);
            }
        }
    }
}

// ============================================================================
// V permutation (unchanged): Vpt[b][h][sb32][hd][ss32], 8KB blobs.
// ============================================================================
__global__ __launch_bounds__(256)
void permute_v(const __hip_bfloat16* __restrict__ QKV,
               __hip_bfloat16* __restrict__ Vpt)
{
    __shared__ __align__(16) __hip_bfloat16 S[64 * 64];
    const int blk = blockIdx.x;
    const int sb = blk & 31, h = (blk >> 5) & 15, b = blk >> 9;
    const int t = threadIdx.x;

    for (int j = 0; j < 2; j++) {
        const int chunk = j * 256 + t;
        const int lrow  = chunk >> 3;
        const int lcol  = (chunk & 7) * 8;
        const int r8 = lrow >> 3, jj = lrow & 7;
        const int srow = r8 * 128 + h * 8 + jj;
        const int scol = sb * 64 + lcol;
        *(uint4*)(S + chunk * 8) =
            *(const uint4*)(QKV + ((size_t)(b * 1024) + srow) * 6144 + 4096 + scol);
    }
    __syncthreads();

    const size_t obase = (((size_t)(b * 16 + h)) * 32 + sb) * 4096;
    for (int i = 0; i < 16; i++) {
        const int lin = t + 256 * i;
        const int hd = lin >> 5, ss = lin & 31;
        Vpt[obase + lin] =
            S[((ss & 7) * 8 + (hd >> 4)) * 64 + (ss >> 3) * 16 + (hd & 15)];
    }
}

// ============================================================================
// Causal flash attention v2 (unchanged from previous round).
// ============================================================================
__global__ __launch_bounds__(256, 2)
void flash_attn(const __hip_bfloat16* __restrict__ QKV,
                const __hip_bfloat16* __restrict__ Vpt,
                __hip_bfloat16* __restrict__ O)   // == QKV buffer
{
    __shared__ __align__(16) __hip_bfloat16 Kt[2][64 * 128];
    __shared__ __align__(16) __hip_bfloat16 Vt[2][2 * 128 * 32];
    __shared__ __align__(16) __hip_bfloat16 Pl[64 * 64];

    const int bid  = blockIdx.x;
    const int pair = bid >> 6;
    const int g    = bid & 63;
    const int b    = g >> 4, h = g & 15;
    const int t    = threadIdx.x;
    const int wave = t >> 6, lane = t & 63;
    const int quad = lane >> 4, l16 = lane & 15;
    const float scale = 0.08838834764831845f;

    const int    rowb  = b * 1024;
    const size_t vbase = (((size_t)(b * 16 + h)) * 32) * 4096;
    const floatx4 zero = {0.f, 0.f, 0.f, 0.f};

    auto stageK = [&](int tk, int bufi) {
        const int kv0 = tk * 64;
        __hip_bfloat16* dst = &Kt[bufi][0];
#pragma unroll
        for (int j = 0; j < 4; j++) {
            const int c0 = (wave * 4 + j) * 64 + lane;
            const int r  = c0 >> 4;
            const int gg = (c0 & 15) ^ (r & 7);
            GLD16(QKV + ((size_t)(rowb + kv0 + r)) * 6144 + 2048 + h * 128 + gg * 8,
                  dst + (wave * 4 + j) * 512);
        }
    };
    auto stageV = [&](int tk, int bufi) {
        const __hip_bfloat16* src = Vpt + vbase + (size_t)(tk * 2) * 4096;
        __hip_bfloat16* dst = &Vt[bufi][0];
#pragma unroll
        for (int j = 0; j < 4; j++) {
            const int c0   = (wave * 4 + j) * 64 + lane;
            const int half = c0 >> 9, w = c0 & 511;
            const int r    = w >> 2;
            const int gg   = (w & 3) ^ (r & 3);
            GLD16(src + half * 4096 + r * 32 + gg * 8,
                  dst + (wave * 4 + j) * 512);
        }
    };

    for (int ph = 0; ph < 2; ++ph) {
        const int qb = ph ? (15 - pair) * 64 : pair * 64;
        const int nt = ph ? 16 - pair       : pair + 1;

        bf16x8 qf[4];
        {
            const size_t rb = ((size_t)(rowb + qb + wave * 16 + l16)) * 6144 + h * 128;
#pragma unroll
            for (int kc = 0; kc < 4; kc++)
                qf[kc] = *(const bf16x8*)(QKV + rb + kc * 32 + quad * 8);
        }

        float m_i[4], l_i[4];
        floatx4 oacc[8];
#pragma unroll
        for (int r = 0; r < 4; r++) { m_i[r] = NEG_BIG; l_i[r] = 0.f; }
#pragma unroll
        for (int ni = 0; ni < 8; ni++) oacc[ni] = zero;

        stageK(0, 0); stageV(0, 0);

        for (int tk = 0; tk < nt; ++tk) {
            const int cur = tk & 1;
            if (tk + 1 < nt) {
                stageK(tk + 1, cur ^ 1); stageV(tk + 1, cur ^ 1);
                asm volatile("s_waitcnt vmcnt(8)" ::: "memory");
            } else {
                asm volatile("s_waitcnt vmcnt(0)" ::: "memory");
            }
            __builtin_amdgcn_s_barrier();
            asm volatile("" ::: "memory");

            const __hip_bfloat16* Kb = &Kt[cur][0];
            const __hip_bfloat16* Vb = &Vt[cur][0];
            const int kv0 = tk * 64;

            floatx4 sc[4];
#pragma unroll
            for (int cbk = 0; cbk < 4; cbk++) {
                floatx4 s = zero;
                const int r  = cbk * 16 + l16;
                const int sw = r & 7;
#pragma unroll
                for (int kc = 0; kc < 4; kc++) {
                    bf16x8 kf = *(const bf16x8*)(
                        Kb + r * 128 + (((kc * 4 + quad) ^ sw) << 3));
                    s = __builtin_amdgcn_mfma_f32_16x16x32_bf16(qf[kc], kf, s, 0, 0, 0);
                }
                sc[cbk] = s;
            }

            const int qrow = qb + wave * 16 + quad * 4;
            if (tk == nt - 1) {
#pragma unroll
                for (int rr = 0; rr < 4; rr++)
#pragma unroll
                    for (int cbk = 0; cbk < 4; cbk++) {
                        const int col = kv0 + cbk * 16 + l16;
                        const float v = sc[cbk][rr] * scale;
                        sc[cbk][rr] = (col > qrow + rr) ? NEG_BIG : v;
                    }
            } else {
#pragma unroll
                for (int rr = 0; rr < 4; rr++)
#pragma unroll
                    for (int cbk = 0; cbk < 4; cbk++) sc[cbk][rr] *= scale;
            }
            float mx[4];
#pragma unroll
            for (int rr = 0; rr < 4; rr++)
                mx[rr] = fmaxf(fmaxf(sc[0][rr], sc[1][rr]),
                               fmaxf(sc[2][rr], sc[3][rr]));
#pragma unroll
            for (int off = 1; off < 16; off <<= 1)
#pragma unroll
                for (int rr = 0; rr < 4; rr++)
                    mx[rr] = fmaxf(mx[rr], __shfl_xor(mx[rr], off));

            float alpha[4], rsum[4];
#pragma unroll
            for (int rr = 0; rr < 4; rr++) {
                const float mnew = fmaxf(m_i[rr], mx[rr]);
                alpha[rr] = __expf(m_i[rr] - mnew);
                m_i[rr] = mnew;
                float acc = 0.f;
#pragma unroll
                for (int cbk = 0; cbk < 4; cbk++) {
                    const float pv = __expf(sc[cbk][rr] - mnew);
                    sc[cbk][rr] = pv;
                    acc += pv;
                }
                rsum[rr] = acc;
            }
#pragma unroll
            for (int off = 1; off < 16; off <<= 1)
#pragma unroll
                for (int rr = 0; rr < 4; rr++)
                    rsum[rr] += __shfl_xor(rsum[rr], off);
#pragma unroll
            for (int rr = 0; rr < 4; rr++)
                l_i[rr] = l_i[rr] * alpha[rr] + rsum[rr];
#pragma unroll
            for (int ni = 0; ni < 8; ni++)
#pragma unroll
                for (int rr = 0; rr < 4; rr++) oacc[ni][rr] *= alpha[rr];

#pragma unroll
            for (int cbk = 0; cbk < 4; cbk++)
#pragma unroll
                for (int rr = 0; rr < 4; rr++) {
                    const int row = wave * 16 + quad * 4 + rr;
                    const int col = cbk * 16 + l16;
                    Pl[row * 64 + ((((col >> 3) ^ (row & 7)) << 3) | (col & 7))] =
                        __float2bfloat16(sc[cbk][rr]);
                }
            asm volatile("s_waitcnt lgkmcnt(0)" ::: "memory");

            const int prow = wave * 16 + l16;
            bf16x8 pf[2];
#pragma unroll
            for (int kc = 0; kc < 2; kc++)
                pf[kc] = *(const bf16x8*)(
                    Pl + prow * 64 + (((kc * 4 + quad) ^ (prow & 7)) << 3));
#pragma unroll
            for (int ni = 0; ni < 8; ni++) {
                const int vr = ni * 16 + l16;
#pragma unroll
                for (int kc = 0; kc < 2; kc++) {
                    bf16x8 vf = *(const bf16x8*)(
                        Vb + kc * 4096 + vr * 32 + (((quad ^ (vr & 3))) << 3));
                    oacc[ni] = __builtin_amdgcn_mfma_f32_16x16x32_bf16(
                        pf[kc], vf, oacc[ni], 0, 0, 0);
                }
            }

            asm volatile("" ::: "memory");
            __builtin_amdgcn_s_barrier();
            asm volatile("" ::: "memory");
        }

        float inv[4];
#pragma unroll
        for (int rr = 0; rr < 4; rr++) inv[rr] = 1.0f / l_i[rr];
#pragma unroll
        for (int ni = 0; ni < 8; ni++)
#pragma unroll
            for (int rr = 0; rr < 4; rr++) {
                const int row = qb + wave * 16 + quad * 4 + rr;
                O[((size_t)rowb + row) * 6144 + 4096 + h * 128 + ni * 16 + l16] =
                    __float2bfloat16(oacc[ni][rr] * inv[rr]);
            }
    }
}

// ============================================================================
extern "C" void kernel_launch(void* const* d_in, const int* in_sizes, int n_in,
                              void* d_out, int out_size, void* d_ws, size_t ws_size,
                              hipStream_t stream) {
    const float* query = (const float*)d_in[0];
    const float* Wqkv = (const float*)d_in[3];
    const float* bqkv = (const float*)d_in[4];
    const float* Wout = (const float*)d_in[5];
    const float* bout = (const float*)d_in[6];
    float* out = (float*)d_out;

    const size_t MB = 1048576;
    char* ws = (char*)d_ws;
    __hip_bfloat16* QKV = (__hip_bfloat16*)ws;
    __hip_bfloat16* Vpt = (__hip_bfloat16*)(ws + 48 * MB);
    __hip_bfloat16* Att = QKV + 4096;            // column offset, lda = 6144

    dim3 blk(256);

    if (ws_size >= 113 * MB) {
        __hip_bfloat16* Qbf     = (__hip_bfloat16*)(ws + 64 * MB);
        __hip_bfloat16* Wqkv_bf = (__hip_bfloat16*)(ws + 80 * MB);
        __hip_bfloat16* Wout_bf = (__hip_bfloat16*)(ws + 104 * MB);

        cvt3_f32_bf16<<<dim3(2048), blk, 0, stream>>>(
            query, (size_t)4096 * 2048 / 8,
            Wqkv,  (size_t)6144 * 2048 / 8,
            Wout,  (size_t)2048 * 2048 / 8,
            Qbf, Wqkv_bf, Wout_bf);
        // QKV projection: 256^2 8-phase kernel, grid 16x24 = 384 (mult of 8)
        gemm256_nt_bias<false><<<dim3(384), dim3(512), 0, stream>>>(
            Qbf, Wqkv_bf, bqkv, QKV, 4096, 6144, 2048, 2048, 2048, 24);
        permute_v<<<dim3(2048), blk, 0, stream>>>(QKV, Vpt);
        flash_attn<<<dim3(512), blk, 0, stream>>>(QKV, Vpt, QKV);
        gemm_nt_bias<false, false, true><<<dim3(16, 32), blk, 0, stream>>>(
            Att, Wout_bf, bout, out, 4096, 2048, 2048, 6144, 2048);
    } else {
        gemm_nt_bias<true, true, false><<<dim3(48, 32), blk, 0, stream>>>(
            query, Wqkv, bqkv, QKV, 4096, 6144, 2048, 2048, 2048);
        permute_v<<<dim3(2048), blk, 0, stream>>>(QKV, Vpt);
        flash_attn<<<dim3(512), blk, 0, stream>>>(QKV, Vpt, QKV);
        gemm_nt_bias<false, true, true><<<dim3(16, 32), blk, 0, stream>>>(
            Att, Wout, bout, out, 4096, 2048, 2048, 6144, 2048);
    }
}

// Round 4
// 381.081 us; speedup vs baseline: 1.5355x; 1.0197x over previous
//
#include <hip/hip_runtime.h>
#include <hip/hip_bf16.h>
#include <stdint.h>

// ---- types ----
typedef __bf16 bf16x8 __attribute__((ext_vector_type(8)));
typedef float  floatx4 __attribute__((ext_vector_type(4)));

#define NEG_BIG (-1e30f)   // finite sentinel: exp(NEG_BIG - m) == 0

// async global->LDS, 16B per lane; LDS dest = wave-uniform base + lane*16
#define GLD16(g, l) __builtin_amdgcn_global_load_lds(                         \
    (__attribute__((address_space(1))) void*)(g),                             \
    (__attribute__((address_space(3))) void*)(l), 16, 0, 0)

// convert 16 fp32 -> 16 bf16, store 32B to LDS
__device__ __forceinline__ void cvt16(const float* __restrict__ s,
                                      __hip_bfloat16* __restrict__ d) {
    float4 f[4];
#pragma unroll
    for (int i = 0; i < 4; i++) f[i] = ((const float4*)s)[i];
    union { __hip_bfloat16 h[16]; uint4 u[2]; } o;
#pragma unroll
    for (int i = 0; i < 4; i++) {
        o.h[4 * i + 0] = __float2bfloat16(f[i].x);
        o.h[4 * i + 1] = __float2bfloat16(f[i].y);
        o.h[4 * i + 2] = __float2bfloat16(f[i].z);
        o.h[4 * i + 3] = __float2bfloat16(f[i].w);
    }
    ((uint4*)d)[0] = o.u[0];
    ((uint4*)d)[1] = o.u[1];
}

// ============================================================================
// Fused fp32->bf16 convert of up to 3 arrays (grid-stride, 8 elems/thread).
// ============================================================================
__global__ __launch_bounds__(256)
void cvt3_f32_bf16(const float* __restrict__ a, size_t na8,
                   const float* __restrict__ b, size_t nb8,
                   const float* __restrict__ c, size_t nc8,
                   __hip_bfloat16* __restrict__ da,
                   __hip_bfloat16* __restrict__ db,
                   __hip_bfloat16* __restrict__ dc)
{
    const size_t total  = na8 + nb8 + nc8;
    const size_t stride = (size_t)gridDim.x * blockDim.x;
    for (size_t idx = (size_t)blockIdx.x * blockDim.x + threadIdx.x;
         idx < total; idx += stride) {
        const float* s; __hip_bfloat16* d; size_t o;
        if (idx < na8)            { s = a; d = da; o = idx; }
        else if (idx < na8 + nb8) { s = b; d = db; o = idx - na8; }
        else                      { s = c; d = dc; o = idx - na8 - nb8; }
        const float4 f0 = ((const float4*)s)[o * 2 + 0];
        const float4 f1 = ((const float4*)s)[o * 2 + 1];
        union { __hip_bfloat16 h[8]; uint4 u; } z;
        z.h[0] = __float2bfloat16(f0.x); z.h[1] = __float2bfloat16(f0.y);
        z.h[2] = __float2bfloat16(f0.z); z.h[3] = __float2bfloat16(f0.w);
        z.h[4] = __float2bfloat16(f1.x); z.h[5] = __float2bfloat16(f1.y);
        z.h[6] = __float2bfloat16(f1.z); z.h[7] = __float2bfloat16(f1.w);
        ((uint4*)d)[o] = z.u;
    }
}

// ============================================================================
// 128x256-tile 8-phase-style NT GEMM: C[M,N] = A[M,K]*B[N,K]^T + bias[N].
// bf16 in, bf16/f32 out. 512 threads = 8 waves (2M x 4N), wave tile 64x64,
// acc[4][4]. BK=64; LDS = 2buf x (A 16KB + B 32KB) = 96KB -> 1 block/CU.
// Grid sizes chosen so blocks/CU is an integer (QKV: 768 = 3/CU; out-proj:
// 256 = 1/CU) -- the round-3 256^2 version lost ~25% to a 1.5-round tail.
//
// 2 phases per K-tile, 16 MFMA each:
//  p0: [ds_read A mi=0,1 (4xb128) + B all (8xb128, held in regs)]
//      [stage TAIL(t+1)={A1,B2,B3} -> buf^1] bar; lgkm0; prio1; 16 MFMA; prio0; bar
//  p1: [ds_read A mi=2,3] [stage HEAD(t+2)={A0,B0,B1} -> buf (dead regions)]
//      bar; lgkm0; prio1; 16 MFMA; prio0; [vmcnt(3) | vmcnt(0)]; bar
// Dead-region proof: A-load j covers rows {j*32..+31} U {64+j*32..+31} which
// is exactly the set phase j consumes (rows wr*64+[j*32,j*32+32), wr=0,1);
// B is fully consumed at p0. HEAD(t+2) is issued after the barrier ending p0
// of tile t, so every wave has finished reading those regions.
// vmcnt(3): in-flight at end of tile t = head(t+1)[3, issued t-1.p1] +
// tail(t+1)[3, t.p0] + head(t+2)[3, t.p1] = 9; waiting to 3 leaves head(t+2)
// in flight with tile t+1 fully resident. Never drains in the main loop.
// XOR swizzle (T2): LDS granule = src granule ^ (row&7), applied on the
// GLD16 *source* and the ds_read address (same involution both sides).
// ============================================================================
template <bool OUT_F32>
__global__ __launch_bounds__(512, 2)
void gemm8p_nt_bias(const __hip_bfloat16* __restrict__ A,
                    const __hip_bfloat16* __restrict__ B,
                    const float* __restrict__ bias, void* __restrict__ Cv,
                    int M, int N, int K, int lda, int ldb, int nby)
{
    __shared__ __align__(16) __hip_bfloat16 Asm[2][128 * 64];
    __shared__ __align__(16) __hip_bfloat16 Bsm[2][256 * 64];

    // XCD swizzle (grid multiple of 8), col-major tile order within chunk
    const int nwg = gridDim.x, cpx = nwg >> 3;
    const int flat = blockIdx.x;
    const int swz  = (flat & 7) * cpx + (flat >> 3);
    const int by = swz % nby, bx = swz / nby;
    const int m0 = by * 128, n0 = bx * 256;

    const int t    = threadIdx.x;
    const int wave = t >> 6, lane = t & 63;
    const int quad = lane >> 4, l16 = lane & 15;
    const int wr   = wave >> 2, wc = wave & 3;   // wave tile 64x64
    const int NT   = K >> 6;

    // ---- staging geometry (8 threads per 64-col row, 16B granules) ----
    const int l8 = lane >> 3;            // 0..7 -> row within wave's 8-row band
    const int g_ = (lane & 7) ^ l8;      // pre-swizzled source granule (row&7==l8)
    const int aRowBase = (wave >> 2) * 64 + (wave & 3) * 8;   // + j*32
    const int bRowBase = wave * 8;                            // + j*64

    auto stageA = [&](int tk, int j, int buf) {
        GLD16(A + (size_t)(m0 + aRowBase + j * 32 + l8) * lda + tk * 64 + g_ * 8,
              &Asm[buf][0] + (aRowBase + j * 32) * 64);
    };
    auto stageB = [&](int tk, int j, int buf) {
        GLD16(B + (size_t)(n0 + bRowBase + j * 64 + l8) * ldb + tk * 64 + g_ * 8,
              &Bsm[buf][0] + (bRowBase + j * 64) * 64);
    };

    // ds_read swizzled granule base: row&7 == l16&7 for all fragment rows
    const int g0 = (quad ^ (l16 & 7)) << 3;    // element offset; ks flips ^32

    floatx4 acc[4][4];
    const floatx4 zero = {0.f, 0.f, 0.f, 0.f};
#pragma unroll
    for (int mi = 0; mi < 4; mi++)
#pragma unroll
        for (int ni = 0; ni < 4; ni++) acc[mi][ni] = zero;

    // ---- prologue: full t0, head(t1); vmcnt(3) leaves head(t1) in flight ----
    stageA(0, 0, 0); stageA(0, 1, 0);
    stageB(0, 0, 0); stageB(0, 1, 0); stageB(0, 2, 0); stageB(0, 3, 0);
    if (NT > 1) {
        stageA(1, 0, 1); stageB(1, 0, 1); stageB(1, 1, 1);
        asm volatile("s_waitcnt vmcnt(3)" ::: "memory");
    } else {
        asm volatile("s_waitcnt vmcnt(0)" ::: "memory");
    }
    __syncthreads();

    int cb = 0;
    for (int tk = 0; tk < NT; ++tk, cb ^= 1) {
        const __hip_bfloat16* Ab = &Asm[cb][0];
        const __hip_bfloat16* Bb = &Bsm[cb][0];
        const int nb = cb ^ 1;

        // ================= phase 0 : mi = 0,1 =================
        bf16x8 af[2][2], bfr[4][2];
#pragma unroll
        for (int i = 0; i < 2; i++)
#pragma unroll
            for (int ks = 0; ks < 2; ks++)
                af[i][ks] = *(const bf16x8*)(
                    Ab + (wr * 64 + i * 16 + l16) * 64 + (g0 ^ (ks ? 32 : 0)));
#pragma unroll
        for (int ni = 0; ni < 4; ni++)
#pragma unroll
            for (int ks = 0; ks < 2; ks++)
                bfr[ni][ks] = *(const bf16x8*)(
                    Bb + (wc * 64 + ni * 16 + l16) * 64 + (g0 ^ (ks ? 32 : 0)));
        if (tk + 1 < NT) {
            stageA(tk + 1, 1, nb); stageB(tk + 1, 2, nb); stageB(tk + 1, 3, nb);
        }
        __builtin_amdgcn_s_barrier();
        asm volatile("s_waitcnt lgkmcnt(0)" ::: "memory");
        __builtin_amdgcn_s_setprio(1);
#pragma unroll
        for (int ks = 0; ks < 2; ks++)
#pragma unroll
            for (int i = 0; i < 2; i++)
#pragma unroll
                for (int ni = 0; ni < 4; ni++)
                    acc[i][ni] = __builtin_amdgcn_mfma_f32_16x16x32_bf16(
                        af[i][ks], bfr[ni][ks], acc[i][ni], 0, 0, 0);
        __builtin_amdgcn_s_setprio(0);
        __builtin_amdgcn_s_barrier();

        // ================= phase 1 : mi = 2,3 =================
#pragma unroll
        for (int i = 0; i < 2; i++)
#pragma unroll
            for (int ks = 0; ks < 2; ks++)
                af[i][ks] = *(const bf16x8*)(
                    Ab + (wr * 64 + (2 + i) * 16 + l16) * 64 + (g0 ^ (ks ? 32 : 0)));
        if (tk + 2 < NT) {
            stageA(tk + 2, 0, cb); stageB(tk + 2, 0, cb); stageB(tk + 2, 1, cb);
        }
        __builtin_amdgcn_s_barrier();
        asm volatile("s_waitcnt lgkmcnt(0)" ::: "memory");
        __builtin_amdgcn_s_setprio(1);
#pragma unroll
        for (int ks = 0; ks < 2; ks++)
#pragma unroll
            for (int i = 0; i < 2; i++)
#pragma unroll
                for (int ni = 0; ni < 4; ni++)
                    acc[2 + i][ni] = __builtin_amdgcn_mfma_f32_16x16x32_bf16(
                        af[i][ks], bfr[ni][ks], acc[2 + i][ni], 0, 0, 0);
        __builtin_amdgcn_s_setprio(0);
        if (tk + 2 < NT)
            asm volatile("s_waitcnt vmcnt(3)" ::: "memory");
        else if (tk + 1 < NT)
            asm volatile("s_waitcnt vmcnt(0)" ::: "memory");
        __builtin_amdgcn_s_barrier();
    }

    // ---- epilogue ----
#pragma unroll
    for (int mi = 0; mi < 4; mi++) {
        const int row = m0 + wr * 64 + mi * 16 + quad * 4;
#pragma unroll
        for (int ni = 0; ni < 4; ni++) {
            const int col = n0 + wc * 64 + ni * 16 + l16;
            const float bv = bias[col];
#pragma unroll
            for (int r = 0; r < 4; r++) {
                const float v = acc[mi][ni][r] + bv;
                if (OUT_F32)
                    ((float*)Cv)[(size_t)(row + r) * N + col] = v;
                else
                    ((__hip_bfloat16*)Cv)[(size_t)(row + r) * N + col] =
                        __float2bfloat16(v);
            }
        }
    }
}

// ============================================================================
// 128x128 NT GEMM (m97 structure) — fp32 fallback path only.
// ============================================================================
template <bool A_F32, bool B_F32, bool OUT_F32>
__global__ __launch_bounds__(256, 2)
void gemm_nt_bias(const void* __restrict__ Av, const void* __restrict__ Bv,
                  const float* __restrict__ bias, void* __restrict__ Cv,
                  int M, int N, int K, int lda, int ldb)
{
    __shared__ __align__(16) __hip_bfloat16 Asm[128 * 32];
    __shared__ __align__(16) __hip_bfloat16 Bsm[128 * 32];
    const int m0   = blockIdx.y * 128;
    const int n0   = blockIdx.x * 128;
    const int t    = threadIdx.x;
    const int wave = t >> 6, lane = t & 63;
    const int quad = lane >> 4, l16 = lane & 15;
    const int wr   = wave >> 1, wc = wave & 1;

    floatx4 zero = {0.f, 0.f, 0.f, 0.f};
    floatx4 acc[4][4];
    for (int i = 0; i < 4; i++)
        for (int j = 0; j < 4; j++) acc[i][j] = zero;

    for (int k0 = 0; k0 < K; k0 += 32) {
        if (A_F32) {
            const float* A = (const float*)Av;
            const int row = t >> 1, half = t & 1;
            cvt16(A + (size_t)(m0 + row) * lda + k0 + half * 16,
                  Asm + row * 32 + half * 16);
        } else {
            const __hip_bfloat16* A = (const __hip_bfloat16*)Av;
            for (int j = 0; j < 2; ++j) {
                const int chunk = (wave * 2 + j) * 64 + lane;
                const int row   = chunk >> 2;
                const int kc    = chunk & 3;
                GLD16(A + (size_t)(m0 + row) * lda + k0 + kc * 8,
                      Asm + (wave * 2 + j) * 512);
            }
        }
        if (B_F32) {
            const float* B = (const float*)Bv;
            const int row = t >> 1, half = t & 1;
            cvt16(B + (size_t)(n0 + row) * ldb + k0 + half * 16,
                  Bsm + row * 32 + half * 16);
        } else {
            const __hip_bfloat16* B = (const __hip_bfloat16*)Bv;
            for (int j = 0; j < 2; ++j) {
                const int chunk = (wave * 2 + j) * 64 + lane;
                const int row   = chunk >> 2;
                const int kc    = chunk & 3;
                GLD16(B + (size_t)(n0 + row) * ldb + k0 + kc * 8,
                      Bsm + (wave * 2 + j) * 512);
            }
        }
        __syncthreads();

        bf16x8 af[4], bf[4];
        for (int i = 0; i < 4; i++) {
            af[i] = *(const bf16x8*)(Asm + (wr * 64 + i * 16 + l16) * 32 + quad * 8);
            bf[i] = *(const bf16x8*)(Bsm + (wc * 64 + i * 16 + l16) * 32 + quad * 8);
        }
        for (int mi = 0; mi < 4; mi++)
            for (int ni = 0; ni < 4; ni++)
                acc[mi][ni] = __builtin_amdgcn_mfma_f32_16x16x32_bf16(
                    af[mi], bf[ni], acc[mi][ni], 0, 0, 0);
        __syncthreads();
    }

    for (int mi = 0; mi < 4; mi++) {
        const int row = m0 + wr * 64 + mi * 16 + quad * 4;
        for (int ni = 0; ni < 4; ni++) {
            const int col = n0 + wc * 64 + ni * 16 + l16;
            const float bv = bias[col];
            for (int r = 0; r < 4; r++) {
                const float v = acc[mi][ni][r] + bv;
                if (OUT_F32)
                    ((float*)Cv)[(size_t)(row + r) * N + col] = v;
                else
                    ((__hip_bfloat16*)Cv)[(size_t)(row + r) * N + col] =
                        __float2bfloat16(v);
            }
        }
    }
}

// ============================================================================
// V permutation (unchanged): Vpt[b][h][sb32][hd][ss32], 8KB blobs.
// ============================================================================
__global__ __launch_bounds__(256)
void permute_v(const __hip_bfloat16* __restrict__ QKV,
               __hip_bfloat16* __restrict__ Vpt)
{
    __shared__ __align__(16) __hip_bfloat16 S[64 * 64];
    const int blk = blockIdx.x;
    const int sb = blk & 31, h = (blk >> 5) & 15, b = blk >> 9;
    const int t = threadIdx.x;

    for (int j = 0; j < 2; j++) {
        const int chunk = j * 256 + t;
        const int lrow  = chunk >> 3;
        const int lcol  = (chunk & 7) * 8;
        const int r8 = lrow >> 3, jj = lrow & 7;
        const int srow = r8 * 128 + h * 8 + jj;
        const int scol = sb * 64 + lcol;
        *(uint4*)(S + chunk * 8) =
            *(const uint4*)(QKV + ((size_t)(b * 1024) + srow) * 6144 + 4096 + scol);
    }
    __syncthreads();

    const size_t obase = (((size_t)(b * 16 + h)) * 32 + sb) * 4096;
    for (int i = 0; i < 16; i++) {
        const int lin = t + 256 * i;
        const int hd = lin >> 5, ss = lin & 31;
        Vpt[obase + lin] =
            S[((ss & 7) * 8 + (hd >> 4)) * 64 + (ss >> 3) * 16 + (hd & 15)];
    }
}

// ============================================================================
// Causal flash attention v2 (unchanged).
// ============================================================================
__global__ __launch_bounds__(256, 2)
void flash_attn(const __hip_bfloat16* __restrict__ QKV,
                const __hip_bfloat16* __restrict__ Vpt,
                __hip_bfloat16* __restrict__ O)   // == QKV buffer
{
    __shared__ __align__(16) __hip_bfloat16 Kt[2][64 * 128];
    __shared__ __align__(16) __hip_bfloat16 Vt[2][2 * 128 * 32];
    __shared__ __align__(16) __hip_bfloat16 Pl[64 * 64];

    const int bid  = blockIdx.x;
    const int pair = bid >> 6;
    const int g    = bid & 63;
    const int b    = g >> 4, h = g & 15;
    const int t    = threadIdx.x;
    const int wave = t >> 6, lane = t & 63;
    const int quad = lane >> 4, l16 = lane & 15;
    const float scale = 0.08838834764831845f;

    const int    rowb  = b * 1024;
    const size_t vbase = (((size_t)(b * 16 + h)) * 32) * 4096;
    const floatx4 zero = {0.f, 0.f, 0.f, 0.f};

    auto stageK = [&](int tk, int bufi) {
        const int kv0 = tk * 64;
        __hip_bfloat16* dst = &Kt[bufi][0];
#pragma unroll
        for (int j = 0; j < 4; j++) {
            const int c0 = (wave * 4 + j) * 64 + lane;
            const int r  = c0 >> 4;
            const int gg = (c0 & 15) ^ (r & 7);
            GLD16(QKV + ((size_t)(rowb + kv0 + r)) * 6144 + 2048 + h * 128 + gg * 8,
                  dst + (wave * 4 + j) * 512);
        }
    };
    auto stageV = [&](int tk, int bufi) {
        const __hip_bfloat16* src = Vpt + vbase + (size_t)(tk * 2) * 4096;
        __hip_bfloat16* dst = &Vt[bufi][0];
#pragma unroll
        for (int j = 0; j < 4; j++) {
            const int c0   = (wave * 4 + j) * 64 + lane;
            const int half = c0 >> 9, w = c0 & 511;
            const int r    = w >> 2;
            const int gg   = (w & 3) ^ (r & 3);
            GLD16(src + half * 4096 + r * 32 + gg * 8,
                  dst + (wave * 4 + j) * 512);
        }
    };

    for (int ph = 0; ph < 2; ++ph) {
        const int qb = ph ? (15 - pair) * 64 : pair * 64;
        const int nt = ph ? 16 - pair       : pair + 1;

        bf16x8 qf[4];
        {
            const size_t rb = ((size_t)(rowb + qb + wave * 16 + l16)) * 6144 + h * 128;
#pragma unroll
            for (int kc = 0; kc < 4; kc++)
                qf[kc] = *(const bf16x8*)(QKV + rb + kc * 32 + quad * 8);
        }

        float m_i[4], l_i[4];
        floatx4 oacc[8];
#pragma unroll
        for (int r = 0; r < 4; r++) { m_i[r] = NEG_BIG; l_i[r] = 0.f; }
#pragma unroll
        for (int ni = 0; ni < 8; ni++) oacc[ni] = zero;

        stageK(0, 0); stageV(0, 0);

        for (int tk = 0; tk < nt; ++tk) {
            const int cur = tk & 1;
            if (tk + 1 < nt) {
                stageK(tk + 1, cur ^ 1); stageV(tk + 1, cur ^ 1);
                asm volatile("s_waitcnt vmcnt(8)" ::: "memory");
            } else {
                asm volatile("s_waitcnt vmcnt(0)" ::: "memory");
            }
            __builtin_amdgcn_s_barrier();
            asm volatile("" ::: "memory");

            const __hip_bfloat16* Kb = &Kt[cur][0];
            const __hip_bfloat16* Vb = &Vt[cur][0];
            const int kv0 = tk * 64;

            floatx4 sc[4];
#pragma unroll
            for (int cbk = 0; cbk < 4; cbk++) {
                floatx4 s = zero;
                const int r  = cbk * 16 + l16;
                const int sw = r & 7;
#pragma unroll
                for (int kc = 0; kc < 4; kc++) {
                    bf16x8 kf = *(const bf16x8*)(
                        Kb + r * 128 + (((kc * 4 + quad) ^ sw) << 3));
                    s = __builtin_amdgcn_mfma_f32_16x16x32_bf16(qf[kc], kf, s, 0, 0, 0);
                }
                sc[cbk] = s;
            }

            const int qrow = qb + wave * 16 + quad * 4;
            if (tk == nt - 1) {
#pragma unroll
                for (int rr = 0; rr < 4; rr++)
#pragma unroll
                    for (int cbk = 0; cbk < 4; cbk++) {
                        const int col = kv0 + cbk * 16 + l16;
                        const float v = sc[cbk][rr] * scale;
                        sc[cbk][rr] = (col > qrow + rr) ? NEG_BIG : v;
                    }
            } else {
#pragma unroll
                for (int rr = 0; rr < 4; rr++)
#pragma unroll
                    for (int cbk = 0; cbk < 4; cbk++) sc[cbk][rr] *= scale;
            }
            float mx[4];
#pragma unroll
            for (int rr = 0; rr < 4; rr++)
                mx[rr] = fmaxf(fmaxf(sc[0][rr], sc[1][rr]),
                               fmaxf(sc[2][rr], sc[3][rr]));
#pragma unroll
            for (int off = 1; off < 16; off <<= 1)
#pragma unroll
                for (int rr = 0; rr < 4; rr++)
                    mx[rr] = fmaxf(mx[rr], __shfl_xor(mx[rr], off));

            float alpha[4], rsum[4];
#pragma unroll
            for (int rr = 0; rr < 4; rr++) {
                const float mnew = fmaxf(m_i[rr], mx[rr]);
                alpha[rr] = __expf(m_i[rr] - mnew);
                m_i[rr] = mnew;
                float acc = 0.f;
#pragma unroll
                for (int cbk = 0; cbk < 4; cbk++) {
                    const float pv = __expf(sc[cbk][rr] - mnew);
                    sc[cbk][rr] = pv;
                    acc += pv;
                }
                rsum[rr] = acc;
            }
#pragma unroll
            for (int off = 1; off < 16; off <<= 1)
#pragma unroll
                for (int rr = 0; rr < 4; rr++)
                    rsum[rr] += __shfl_xor(rsum[rr], off);
#pragma unroll
            for (int rr = 0; rr < 4; rr++)
                l_i[rr] = l_i[rr] * alpha[rr] + rsum[rr];
#pragma unroll
            for (int ni = 0; ni < 8; ni++)
#pragma unroll
                for (int rr = 0; rr < 4; rr++) oacc[ni][rr] *= alpha[rr];

#pragma unroll
            for (int cbk = 0; cbk < 4; cbk++)
#pragma unroll
                for (int rr = 0; rr < 4; rr++) {
                    const int row = wave * 16 + quad * 4 + rr;
                    const int col = cbk * 16 + l16;
                    Pl[row * 64 + ((((col >> 3) ^ (row & 7)) << 3) | (col & 7))] =
                        __float2bfloat16(sc[cbk][rr]);
                }
            asm volatile("s_waitcnt lgkmcnt(0)" ::: "memory");

            const int prow = wave * 16 + l16;
            bf16x8 pf[2];
#pragma unroll
            for (int kc = 0; kc < 2; kc++)
                pf[kc] = *(const bf16x8*)(
                    Pl + prow * 64 + (((kc * 4 + quad) ^ (prow & 7)) << 3));
#pragma unroll
            for (int ni = 0; ni < 8; ni++) {
                const int vr = ni * 16 + l16;
#pragma unroll
                for (int kc = 0; kc < 2; kc++) {
                    bf16x8 vf = *(const bf16x8*)(
                        Vb + kc * 4096 + vr * 32 + (((quad ^ (vr & 3))) << 3));
                    oacc[ni] = __builtin_amdgcn_mfma_f32_16x16x32_bf16(
                        pf[kc], vf, oacc[ni], 0, 0, 0);
                }
            }

            asm volatile("" ::: "memory");
            __builtin_amdgcn_s_barrier();
            asm volatile("" ::: "memory");
        }

        float inv[4];
#pragma unroll
        for (int rr = 0; rr < 4; rr++) inv[rr] = 1.0f / l_i[rr];
#pragma unroll
        for (int ni = 0; ni < 8; ni++)
#pragma unroll
            for (int rr = 0; rr < 4; rr++) {
                const int row = qb + wave * 16 + quad * 4 + rr;
                O[((size_t)rowb + row) * 6144 + 4096 + h * 128 + ni * 16 + l16] =
                    __float2bfloat16(oacc[ni][rr] * inv[rr]);
            }
    }
}

// ============================================================================
extern "C" void kernel_launch(void* const* d_in, const int* in_sizes, int n_in,
                              void* d_out, int out_size, void* d_ws, size_t ws_size,
                              hipStream_t stream) {
    const float* query = (const float*)d_in[0];
    const float* Wqkv = (const float*)d_in[3];
    const float* bqkv = (const float*)d_in[4];
    const float* Wout = (const float*)d_in[5];
    const float* bout = (const float*)d_in[6];
    float* out = (float*)d_out;

    const size_t MB = 1048576;
    char* ws = (char*)d_ws;
    __hip_bfloat16* QKV = (__hip_bfloat16*)ws;
    __hip_bfloat16* Vpt = (__hip_bfloat16*)(ws + 48 * MB);
    __hip_bfloat16* Att = QKV + 4096;            // column offset, lda = 6144

    dim3 blk(256);

    if (ws_size >= 113 * MB) {
        __hip_bfloat16* Qbf     = (__hip_bfloat16*)(ws + 64 * MB);
        __hip_bfloat16* Wqkv_bf = (__hip_bfloat16*)(ws + 80 * MB);
        __hip_bfloat16* Wout_bf = (__hip_bfloat16*)(ws + 104 * MB);

        cvt3_f32_bf16<<<dim3(2048), blk, 0, stream>>>(
            query, (size_t)4096 * 2048 / 8,
            Wqkv,  (size_t)6144 * 2048 / 8,
            Wout,  (size_t)2048 * 2048 / 8,
            Qbf, Wqkv_bf, Wout_bf);
        // QKV projection: 128x256 tiles, grid 32x24 = 768 = exactly 3/CU
        gemm8p_nt_bias<false><<<dim3(768), dim3(512), 0, stream>>>(
            Qbf, Wqkv_bf, bqkv, QKV, 4096, 6144, 2048, 2048, 2048, 32);
        permute_v<<<dim3(2048), blk, 0, stream>>>(QKV, Vpt);
        flash_attn<<<dim3(512), blk, 0, stream>>>(QKV, Vpt, QKV);
        // out projection: 128x256 tiles, grid 32x8 = 256 = exactly 1/CU
        gemm8p_nt_bias<true><<<dim3(256), dim3(512), 0, stream>>>(
            Att, Wout_bf, bout, out, 4096, 2048, 2048, 6144, 2048, 32);
    } else {
        gemm_nt_bias<true, true, false><<<dim3(48, 32), blk, 0, stream>>>(
            query, Wqkv, bqkv, QKV, 4096, 6144, 2048, 2048, 2048);
        permute_v<<<dim3(2048), blk, 0, stream>>>(QKV, Vpt);
        flash_attn<<<dim3(512), blk, 0, stream>>>(QKV, Vpt, QKV);
        gemm_nt_bias<false, true, true><<<dim3(16, 32), blk, 0, stream>>>(
            Att, Wout, bout, out, 4096, 2048, 2048, 6144, 2048);
    }
}

// Round 5
// 358.140 us; speedup vs baseline: 1.6338x; 1.0641x over previous
//
#include <hip/hip_runtime.h>
#include <hip/hip_bf16.h>
#include <stdint.h>

// ---- types ----
typedef __bf16 bf16x8 __attribute__((ext_vector_type(8)));
typedef float  floatx4 __attribute__((ext_vector_type(4)));

#define NEG_BIG (-1e30f)   // finite sentinel: exp(NEG_BIG - m) == 0

// async global->LDS, 16B per lane; LDS dest = wave-uniform base + lane*16
#define GLD16(g, l) __builtin_amdgcn_global_load_lds(                         \
    (__attribute__((address_space(1))) void*)(g),                             \
    (__attribute__((address_space(3))) void*)(l), 16, 0, 0)

// convert 16 fp32 -> 16 bf16, store 32B to LDS
__device__ __forceinline__ void cvt16(const float* __restrict__ s,
                                      __hip_bfloat16* __restrict__ d) {
    float4 f[4];
#pragma unroll
    for (int i = 0; i < 4; i++) f[i] = ((const float4*)s)[i];
    union { __hip_bfloat16 h[16]; uint4 u[2]; } o;
#pragma unroll
    for (int i = 0; i < 4; i++) {
        o.h[4 * i + 0] = __float2bfloat16(f[i].x);
        o.h[4 * i + 1] = __float2bfloat16(f[i].y);
        o.h[4 * i + 2] = __float2bfloat16(f[i].z);
        o.h[4 * i + 3] = __float2bfloat16(f[i].w);
    }
    ((uint4*)d)[0] = o.u[0];
    ((uint4*)d)[1] = o.u[1];
}

// ============================================================================
// Fused fp32->bf16 convert of up to 3 arrays (grid-stride, 8 elems/thread).
// ============================================================================
__global__ __launch_bounds__(256)
void cvt3_f32_bf16(const float* __restrict__ a, size_t na8,
                   const float* __restrict__ b, size_t nb8,
                   const float* __restrict__ c, size_t nc8,
                   __hip_bfloat16* __restrict__ da,
                   __hip_bfloat16* __restrict__ db,
                   __hip_bfloat16* __restrict__ dc)
{
    const size_t total  = na8 + nb8 + nc8;
    const size_t stride = (size_t)gridDim.x * blockDim.x;
    for (size_t idx = (size_t)blockIdx.x * blockDim.x + threadIdx.x;
         idx < total; idx += stride) {
        const float* s; __hip_bfloat16* d; size_t o;
        if (idx < na8)            { s = a; d = da; o = idx; }
        else if (idx < na8 + nb8) { s = b; d = db; o = idx - na8; }
        else                      { s = c; d = dc; o = idx - na8 - nb8; }
        const float4 f0 = ((const float4*)s)[o * 2 + 0];
        const float4 f1 = ((const float4*)s)[o * 2 + 1];
        union { __hip_bfloat16 h[8]; uint4 u; } z;
        z.h[0] = __float2bfloat16(f0.x); z.h[1] = __float2bfloat16(f0.y);
        z.h[2] = __float2bfloat16(f0.z); z.h[3] = __float2bfloat16(f0.w);
        z.h[4] = __float2bfloat16(f1.x); z.h[5] = __float2bfloat16(f1.y);
        z.h[6] = __float2bfloat16(f1.z); z.h[7] = __float2bfloat16(f1.w);
        ((uint4*)d)[o] = z.u;
    }
}

// ============================================================================
// 128x192-tile NT GEMM, 2 blocks/CU: C = A[M,K]*B[N,K]^T + bias. bf16->bf16.
// 256 threads = 4 waves (2M x 2N), wave tile 64x96, acc[4][6] -> 48 MFMA per
// wave per K-tile (1.5x the 128x256 kernel). LDS = 2buf x (A 16KB + B 24KB)
// = 80KB -> exactly 2 blocks/CU (160KB). Two co-resident blocks are
// barrier-DEcoupled: one block's barrier/vmcnt stall is hidden by the other
// block's MFMAs (m114 mechanism). Grid must be 1024 = 32by x 32bx (M=4096,
// N=6144), K%64==0.
//
// 2 phases per K-tile, 24 MFMA each (mi pair x 6 ni x 2 ks):
//  p0: ds_read A(mi0,1) 4xb128 + B all 12xb128 (held in regs);
//      issue TAIL(t+1)={A1,A3,B3,B4,B5} -> buf^1; bar; lgkm0; prio1;
//      24 MFMA; prio0; bar
//  p1: ds_read A(mi2,3); issue HEAD(t+2)={A0,A2,B0,B1,B2} -> cur buf (dead:
//      A-loads j0/j2 = rows {0-31,64-95} consumed in p0; B consumed in p0);
//      bar; lgkm0; prio1; 24 MFMA; prio0; [vmcnt(5)|vmcnt(0)]; bar
// In-flight at end of t.p1 = tail(t+1)[5] + head(t+2)[5] = 10; vmcnt(5)
// leaves head(t+2) in flight with t+1 fully resident. Never drains in-loop.
// A-load j covers rows [32j,32j+32); phase p consumes A rows
// wr*64+[32p,32p+32) = loads {j=p, j=p+2}. XOR swizzle: LDS granule holds
// source granule (g ^ row&7), applied on GLD16 source and ds_read address.
// XCD 2D chunk map: xcd c=flat&7 owns a 16by x 8bx sub-grid (by-origin
// (c&1)*16, bx-origin (c>>1)*8) -> per-XCD footprint A 8MB + B 6MB.
// ============================================================================
__global__ __launch_bounds__(256, 2)
void gemm2b_nt_bias(const __hip_bfloat16* __restrict__ A,
                    const __hip_bfloat16* __restrict__ B,
                    const float* __restrict__ bias,
                    __hip_bfloat16* __restrict__ C,
                    int M, int N, int K, int lda, int ldb)
{
    __shared__ __align__(16) __hip_bfloat16 Asm[2][128 * 64];
    __shared__ __align__(16) __hip_bfloat16 Bsm[2][192 * 64];

    // 2D XCD chunk mapping (grid 1024 = 32 x 32)
    const int flat = blockIdx.x;
    const int c    = flat & 7;          // XCD (round-robin dispatch)
    const int i_   = flat >> 3;         // 0..127 within chunk
    const int by = (c & 1) * 16 + (i_ & 15);
    const int bx = (c >> 1) * 8 + (i_ >> 4);
    const int m0 = by * 128, n0 = bx * 192;

    const int t    = threadIdx.x;
    const int wave = t >> 6, lane = t & 63;
    const int quad = lane >> 4, l16 = lane & 15;
    const int wr   = wave >> 1, wc = wave & 1;   // wave tile 64x96
    const int NT   = K >> 6;

    // ---- staging geometry: one GLD16-call = 256 thr x 16B = 32 rows ----
    const int l8 = lane >> 3;            // row within wave's 8-row slice
    const int g_ = (lane & 7) ^ l8;      // pre-swizzled source granule
    auto stageA = [&](int tk, int j, int buf) {
        GLD16(A + (size_t)(m0 + j * 32 + wave * 8 + l8) * lda + tk * 64 + g_ * 8,
              &Asm[buf][0] + (j * 32 + wave * 8) * 64);
    };
    auto stageB = [&](int tk, int j, int buf) {
        GLD16(B + (size_t)(n0 + j * 32 + wave * 8 + l8) * ldb + tk * 64 + g_ * 8,
              &Bsm[buf][0] + (j * 32 + wave * 8) * 64);
    };

    // ds_read swizzled granule base (row&7 == l16&7 for fragment rows)
    const int g0 = (quad ^ (l16 & 7)) << 3;   // element offset; ks flips ^32

    floatx4 acc[4][6];
    const floatx4 zero = {0.f, 0.f, 0.f, 0.f};
#pragma unroll
    for (int mi = 0; mi < 4; mi++)
#pragma unroll
        for (int ni = 0; ni < 6; ni++) acc[mi][ni] = zero;

    // ---- prologue: full t0 (10 loads), head(t1) (5); vmcnt(5) ----
#pragma unroll
    for (int j = 0; j < 4; j++) stageA(0, j, 0);
#pragma unroll
    for (int j = 0; j < 6; j++) stageB(0, j, 0);
    if (NT > 1) {
        stageA(1, 0, 1); stageA(1, 2, 1);
        stageB(1, 0, 1); stageB(1, 1, 1); stageB(1, 2, 1);
        asm volatile("s_waitcnt vmcnt(5)" ::: "memory");
    } else {
        asm volatile("s_waitcnt vmcnt(0)" ::: "memory");
    }
    __syncthreads();

    int cb = 0;
    for (int tk = 0; tk < NT; ++tk, cb ^= 1) {
        const __hip_bfloat16* Ab = &Asm[cb][0];
        const __hip_bfloat16* Bb = &Bsm[cb][0];
        const int nb = cb ^ 1;

        // ================= phase 0 : mi = 0,1 =================
        bf16x8 af[2][2], bfr[6][2];
#pragma unroll
        for (int i = 0; i < 2; i++)
#pragma unroll
            for (int ks = 0; ks < 2; ks++)
                af[i][ks] = *(const bf16x8*)(
                    Ab + (wr * 64 + i * 16 + l16) * 64 + (g0 ^ (ks ? 32 : 0)));
#pragma unroll
        for (int ni = 0; ni < 6; ni++)
#pragma unroll
            for (int ks = 0; ks < 2; ks++)
                bfr[ni][ks] = *(const bf16x8*)(
                    Bb + (wc * 96 + ni * 16 + l16) * 64 + (g0 ^ (ks ? 32 : 0)));
        if (tk + 1 < NT) {
            stageA(tk + 1, 1, nb); stageA(tk + 1, 3, nb);
            stageB(tk + 1, 3, nb); stageB(tk + 1, 4, nb); stageB(tk + 1, 5, nb);
        }
        __builtin_amdgcn_s_barrier();
        asm volatile("s_waitcnt lgkmcnt(0)" ::: "memory");
        __builtin_amdgcn_s_setprio(1);
#pragma unroll
        for (int ks = 0; ks < 2; ks++)
#pragma unroll
            for (int i = 0; i < 2; i++)
#pragma unroll
                for (int ni = 0; ni < 6; ni++)
                    acc[i][ni] = __builtin_amdgcn_mfma_f32_16x16x32_bf16(
                        af[i][ks], bfr[ni][ks], acc[i][ni], 0, 0, 0);
        __builtin_amdgcn_s_setprio(0);
        __builtin_amdgcn_s_barrier();

        // ================= phase 1 : mi = 2,3 =================
#pragma unroll
        for (int i = 0; i < 2; i++)
#pragma unroll
            for (int ks = 0; ks < 2; ks++)
                af[i][ks] = *(const bf16x8*)(
                    Ab + (wr * 64 + (2 + i) * 16 + l16) * 64 + (g0 ^ (ks ? 32 : 0)));
        if (tk + 2 < NT) {
            stageA(tk + 2, 0, cb); stageA(tk + 2, 2, cb);
            stageB(tk + 2, 0, cb); stageB(tk + 2, 1, cb); stageB(tk + 2, 2, cb);
        }
        __builtin_amdgcn_s_barrier();
        asm volatile("s_waitcnt lgkmcnt(0)" ::: "memory");
        __builtin_amdgcn_s_setprio(1);
#pragma unroll
        for (int ks = 0; ks < 2; ks++)
#pragma unroll
            for (int i = 0; i < 2; i++)
#pragma unroll
                for (int ni = 0; ni < 6; ni++)
                    acc[2 + i][ni] = __builtin_amdgcn_mfma_f32_16x16x32_bf16(
                        af[i][ks], bfr[ni][ks], acc[2 + i][ni], 0, 0, 0);
        __builtin_amdgcn_s_setprio(0);
        if (tk + 2 < NT)
            asm volatile("s_waitcnt vmcnt(5)" ::: "memory");
        else if (tk + 1 < NT)
            asm volatile("s_waitcnt vmcnt(0)" ::: "memory");
        __builtin_amdgcn_s_barrier();
    }

    // ---- epilogue ----
#pragma unroll
    for (int mi = 0; mi < 4; mi++) {
        const int row = m0 + wr * 64 + mi * 16 + quad * 4;
#pragma unroll
        for (int ni = 0; ni < 6; ni++) {
            const int col = n0 + wc * 96 + ni * 16 + l16;
            const float bv = bias[col];
#pragma unroll
            for (int r = 0; r < 4; r++)
                C[(size_t)(row + r) * N + col] =
                    __float2bfloat16(acc[mi][ni][r] + bv);
        }
    }
}

// ============================================================================
// 128x256-tile 8-phase-style NT GEMM (round-4 kernel) — used for out-proj
// (grid 256 = exactly 1/CU). See round-4 comments for schedule proof.
// ============================================================================
template <bool OUT_F32>
__global__ __launch_bounds__(512, 2)
void gemm8p_nt_bias(const __hip_bfloat16* __restrict__ A,
                    const __hip_bfloat16* __restrict__ B,
                    const float* __restrict__ bias, void* __restrict__ Cv,
                    int M, int N, int K, int lda, int ldb, int nby)
{
    __shared__ __align__(16) __hip_bfloat16 Asm[2][128 * 64];
    __shared__ __align__(16) __hip_bfloat16 Bsm[2][256 * 64];

    const int nwg = gridDim.x, cpx = nwg >> 3;
    const int flat = blockIdx.x;
    const int swz  = (flat & 7) * cpx + (flat >> 3);
    const int by = swz % nby, bx = swz / nby;
    const int m0 = by * 128, n0 = bx * 256;

    const int t    = threadIdx.x;
    const int wave = t >> 6, lane = t & 63;
    const int quad = lane >> 4, l16 = lane & 15;
    const int wr   = wave >> 2, wc = wave & 3;
    const int NT   = K >> 6;

    const int l8 = lane >> 3;
    const int g_ = (lane & 7) ^ l8;
    const int aRowBase = (wave >> 2) * 64 + (wave & 3) * 8;
    const int bRowBase = wave * 8;

    auto stageA = [&](int tk, int j, int buf) {
        GLD16(A + (size_t)(m0 + aRowBase + j * 32 + l8) * lda + tk * 64 + g_ * 8,
              &Asm[buf][0] + (aRowBase + j * 32) * 64);
    };
    auto stageB = [&](int tk, int j, int buf) {
        GLD16(B + (size_t)(n0 + bRowBase + j * 64 + l8) * ldb + tk * 64 + g_ * 8,
              &Bsm[buf][0] + (bRowBase + j * 64) * 64);
    };

    const int g0 = (quad ^ (l16 & 7)) << 3;

    floatx4 acc[4][4];
    const floatx4 zero = {0.f, 0.f, 0.f, 0.f};
#pragma unroll
    for (int mi = 0; mi < 4; mi++)
#pragma unroll
        for (int ni = 0; ni < 4; ni++) acc[mi][ni] = zero;

    stageA(0, 0, 0); stageA(0, 1, 0);
    stageB(0, 0, 0); stageB(0, 1, 0); stageB(0, 2, 0); stageB(0, 3, 0);
    if (NT > 1) {
        stageA(1, 0, 1); stageB(1, 0, 1); stageB(1, 1, 1);
        asm volatile("s_waitcnt vmcnt(3)" ::: "memory");
    } else {
        asm volatile("s_waitcnt vmcnt(0)" ::: "memory");
    }
    __syncthreads();

    int cb = 0;
    for (int tk = 0; tk < NT; ++tk, cb ^= 1) {
        const __hip_bfloat16* Ab = &Asm[cb][0];
        const __hip_bfloat16* Bb = &Bsm[cb][0];
        const int nb = cb ^ 1;

        bf16x8 af[2][2], bfr[4][2];
#pragma unroll
        for (int i = 0; i < 2; i++)
#pragma unroll
            for (int ks = 0; ks < 2; ks++)
                af[i][ks] = *(const bf16x8*)(
                    Ab + (wr * 64 + i * 16 + l16) * 64 + (g0 ^ (ks ? 32 : 0)));
#pragma unroll
        for (int ni = 0; ni < 4; ni++)
#pragma unroll
            for (int ks = 0; ks < 2; ks++)
                bfr[ni][ks] = *(const bf16x8*)(
                    Bb + (wc * 64 + ni * 16 + l16) * 64 + (g0 ^ (ks ? 32 : 0)));
        if (tk + 1 < NT) {
            stageA(tk + 1, 1, nb); stageB(tk + 1, 2, nb); stageB(tk + 1, 3, nb);
        }
        __builtin_amdgcn_s_barrier();
        asm volatile("s_waitcnt lgkmcnt(0)" ::: "memory");
        __builtin_amdgcn_s_setprio(1);
#pragma unroll
        for (int ks = 0; ks < 2; ks++)
#pragma unroll
            for (int i = 0; i < 2; i++)
#pragma unroll
                for (int ni = 0; ni < 4; ni++)
                    acc[i][ni] = __builtin_amdgcn_mfma_f32_16x16x32_bf16(
                        af[i][ks], bfr[ni][ks], acc[i][ni], 0, 0, 0);
        __builtin_amdgcn_s_setprio(0);
        __builtin_amdgcn_s_barrier();

#pragma unroll
        for (int i = 0; i < 2; i++)
#pragma unroll
            for (int ks = 0; ks < 2; ks++)
                af[i][ks] = *(const bf16x8*)(
                    Ab + (wr * 64 + (2 + i) * 16 + l16) * 64 + (g0 ^ (ks ? 32 : 0)));
        if (tk + 2 < NT) {
            stageA(tk + 2, 0, cb); stageB(tk + 2, 0, cb); stageB(tk + 2, 1, cb);
        }
        __builtin_amdgcn_s_barrier();
        asm volatile("s_waitcnt lgkmcnt(0)" ::: "memory");
        __builtin_amdgcn_s_setprio(1);
#pragma unroll
        for (int ks = 0; ks < 2; ks++)
#pragma unroll
            for (int i = 0; i < 2; i++)
#pragma unroll
                for (int ni = 0; ni < 4; ni++)
                    acc[2 + i][ni] = __builtin_amdgcn_mfma_f32_16x16x32_bf16(
                        af[i][ks], bfr[ni][ks], acc[2 + i][ni], 0, 0, 0);
        __builtin_amdgcn_s_setprio(0);
        if (tk + 2 < NT)
            asm volatile("s_waitcnt vmcnt(3)" ::: "memory");
        else if (tk + 1 < NT)
            asm volatile("s_waitcnt vmcnt(0)" ::: "memory");
        __builtin_amdgcn_s_barrier();
    }

#pragma unroll
    for (int mi = 0; mi < 4; mi++) {
        const int row = m0 + wr * 64 + mi * 16 + quad * 4;
#pragma unroll
        for (int ni = 0; ni < 4; ni++) {
            const int col = n0 + wc * 64 + ni * 16 + l16;
            const float bv = bias[col];
#pragma unroll
            for (int r = 0; r < 4; r++) {
                const float v = acc[mi][ni][r] + bv;
                if (OUT_F32)
                    ((float*)Cv)[(size_t)(row + r) * N + col] = v;
                else
                    ((__hip_bfloat16*)Cv)[(size_t)(row + r) * N + col] =
                        __float2bfloat16(v);
            }
        }
    }
}

// ============================================================================
// 128x128 NT GEMM (m97 structure) — fp32 fallback path only.
// ============================================================================
template <bool A_F32, bool B_F32, bool OUT_F32>
__global__ __launch_bounds__(256, 2)
void gemm_nt_bias(const void* __restrict__ Av, const void* __restrict__ Bv,
                  const float* __restrict__ bias, void* __restrict__ Cv,
                  int M, int N, int K, int lda, int ldb)
{
    __shared__ __align__(16) __hip_bfloat16 Asm[128 * 32];
    __shared__ __align__(16) __hip_bfloat16 Bsm[128 * 32];
    const int m0   = blockIdx.y * 128;
    const int n0   = blockIdx.x * 128;
    const int t    = threadIdx.x;
    const int wave = t >> 6, lane = t & 63;
    const int quad = lane >> 4, l16 = lane & 15;
    const int wr   = wave >> 1, wc = wave & 1;

    floatx4 zero = {0.f, 0.f, 0.f, 0.f};
    floatx4 acc[4][4];
    for (int i = 0; i < 4; i++)
        for (int j = 0; j < 4; j++) acc[i][j] = zero;

    for (int k0 = 0; k0 < K; k0 += 32) {
        if (A_F32) {
            const float* A = (const float*)Av;
            const int row = t >> 1, half = t & 1;
            cvt16(A + (size_t)(m0 + row) * lda + k0 + half * 16,
                  Asm + row * 32 + half * 16);
        } else {
            const __hip_bfloat16* A = (const __hip_bfloat16*)Av;
            for (int j = 0; j < 2; ++j) {
                const int chunk = (wave * 2 + j) * 64 + lane;
                const int row   = chunk >> 2;
                const int kc    = chunk & 3;
                GLD16(A + (size_t)(m0 + row) * lda + k0 + kc * 8,
                      Asm + (wave * 2 + j) * 512);
            }
        }
        if (B_F32) {
            const float* B = (const float*)Bv;
            const int row = t >> 1, half = t & 1;
            cvt16(B + (size_t)(n0 + row) * ldb + k0 + half * 16,
                  Bsm + row * 32 + half * 16);
        } else {
            const __hip_bfloat16* B = (const __hip_bfloat16*)Bv;
            for (int j = 0; j < 2; ++j) {
                const int chunk = (wave * 2 + j) * 64 + lane;
                const int row   = chunk >> 2;
                const int kc    = chunk & 3;
                GLD16(B + (size_t)(n0 + row) * ldb + k0 + kc * 8,
                      Bsm + (wave * 2 + j) * 512);
            }
        }
        __syncthreads();

        bf16x8 af[4], bf[4];
        for (int i = 0; i < 4; i++) {
            af[i] = *(const bf16x8*)(Asm + (wr * 64 + i * 16 + l16) * 32 + quad * 8);
            bf[i] = *(const bf16x8*)(Bsm + (wc * 64 + i * 16 + l16) * 32 + quad * 8);
        }
        for (int mi = 0; mi < 4; mi++)
            for (int ni = 0; ni < 4; ni++)
                acc[mi][ni] = __builtin_amdgcn_mfma_f32_16x16x32_bf16(
                    af[mi], bf[ni], acc[mi][ni], 0, 0, 0);
        __syncthreads();
    }

    for (int mi = 0; mi < 4; mi++) {
        const int row = m0 + wr * 64 + mi * 16 + quad * 4;
        for (int ni = 0; ni < 4; ni++) {
            const int col = n0 + wc * 64 + ni * 16 + l16;
            const float bv = bias[col];
            for (int r = 0; r < 4; r++) {
                const float v = acc[mi][ni][r] + bv;
                if (OUT_F32)
                    ((float*)Cv)[(size_t)(row + r) * N + col] = v;
                else
                    ((__hip_bfloat16*)Cv)[(size_t)(row + r) * N + col] =
                        __float2bfloat16(v);
            }
        }
    }
}

// ============================================================================
// V permutation (unchanged): Vpt[b][h][sb32][hd][ss32], 8KB blobs.
// ============================================================================
__global__ __launch_bounds__(256)
void permute_v(const __hip_bfloat16* __restrict__ QKV,
               __hip_bfloat16* __restrict__ Vpt)
{
    __shared__ __align__(16) __hip_bfloat16 S[64 * 64];
    const int blk = blockIdx.x;
    const int sb = blk & 31, h = (blk >> 5) & 15, b = blk >> 9;
    const int t = threadIdx.x;

    for (int j = 0; j < 2; j++) {
        const int chunk = j * 256 + t;
        const int lrow  = chunk >> 3;
        const int lcol  = (chunk & 7) * 8;
        const int r8 = lrow >> 3, jj = lrow & 7;
        const int srow = r8 * 128 + h * 8 + jj;
        const int scol = sb * 64 + lcol;
        *(uint4*)(S + chunk * 8) =
            *(const uint4*)(QKV + ((size_t)(b * 1024) + srow) * 6144 + 4096 + scol);
    }
    __syncthreads();

    const size_t obase = (((size_t)(b * 16 + h)) * 32 + sb) * 4096;
    for (int i = 0; i < 16; i++) {
        const int lin = t + 256 * i;
        const int hd = lin >> 5, ss = lin & 31;
        Vpt[obase + lin] =
            S[((ss & 7) * 8 + (hd >> 4)) * 64 + (ss >> 3) * 16 + (hd & 15)];
    }
}

// ============================================================================
// Causal flash attention v2 (unchanged).
// ============================================================================
__global__ __launch_bounds__(256, 2)
void flash_attn(const __hip_bfloat16* __restrict__ QKV,
                const __hip_bfloat16* __restrict__ Vpt,
                __hip_bfloat16* __restrict__ O)   // == QKV buffer
{
    __shared__ __align__(16) __hip_bfloat16 Kt[2][64 * 128];
    __shared__ __align__(16) __hip_bfloat16 Vt[2][2 * 128 * 32];
    __shared__ __align__(16) __hip_bfloat16 Pl[64 * 64];

    const int bid  = blockIdx.x;
    const int pair = bid >> 6;
    const int g    = bid & 63;
    const int b    = g >> 4, h = g & 15;
    const int t    = threadIdx.x;
    const int wave = t >> 6, lane = t & 63;
    const int quad = lane >> 4, l16 = lane & 15;
    const float scale = 0.08838834764831845f;

    const int    rowb  = b * 1024;
    const size_t vbase = (((size_t)(b * 16 + h)) * 32) * 4096;
    const floatx4 zero = {0.f, 0.f, 0.f, 0.f};

    auto stageK = [&](int tk, int bufi) {
        const int kv0 = tk * 64;
        __hip_bfloat16* dst = &Kt[bufi][0];
#pragma unroll
        for (int j = 0; j < 4; j++) {
            const int c0 = (wave * 4 + j) * 64 + lane;
            const int r  = c0 >> 4;
            const int gg = (c0 & 15) ^ (r & 7);
            GLD16(QKV + ((size_t)(rowb + kv0 + r)) * 6144 + 2048 + h * 128 + gg * 8,
                  dst + (wave * 4 + j) * 512);
        }
    };
    auto stageV = [&](int tk, int bufi) {
        const __hip_bfloat16* src = Vpt + vbase + (size_t)(tk * 2) * 4096;
        __hip_bfloat16* dst = &Vt[bufi][0];
#pragma unroll
        for (int j = 0; j < 4; j++) {
            const int c0   = (wave * 4 + j) * 64 + lane;
            const int half = c0 >> 9, w = c0 & 511;
            const int r    = w >> 2;
            const int gg   = (w & 3) ^ (r & 3);
            GLD16(src + half * 4096 + r * 32 + gg * 8,
                  dst + (wave * 4 + j) * 512);
        }
    };

    for (int ph = 0; ph < 2; ++ph) {
        const int qb = ph ? (15 - pair) * 64 : pair * 64;
        const int nt = ph ? 16 - pair       : pair + 1;

        bf16x8 qf[4];
        {
            const size_t rb = ((size_t)(rowb + qb + wave * 16 + l16)) * 6144 + h * 128;
#pragma unroll
            for (int kc = 0; kc < 4; kc++)
                qf[kc] = *(const bf16x8*)(QKV + rb + kc * 32 + quad * 8);
        }

        float m_i[4], l_i[4];
        floatx4 oacc[8];
#pragma unroll
        for (int r = 0; r < 4; r++) { m_i[r] = NEG_BIG; l_i[r] = 0.f; }
#pragma unroll
        for (int ni = 0; ni < 8; ni++) oacc[ni] = zero;

        stageK(0, 0); stageV(0, 0);

        for (int tk = 0; tk < nt; ++tk) {
            const int cur = tk & 1;
            if (tk + 1 < nt) {
                stageK(tk + 1, cur ^ 1); stageV(tk + 1, cur ^ 1);
                asm volatile("s_waitcnt vmcnt(8)" ::: "memory");
            } else {
                asm volatile("s_waitcnt vmcnt(0)" ::: "memory");
            }
            __builtin_amdgcn_s_barrier();
            asm volatile("" ::: "memory");

            const __hip_bfloat16* Kb = &Kt[cur][0];
            const __hip_bfloat16* Vb = &Vt[cur][0];
            const int kv0 = tk * 64;

            floatx4 sc[4];
#pragma unroll
            for (int cbk = 0; cbk < 4; cbk++) {
                floatx4 s = zero;
                const int r  = cbk * 16 + l16;
                const int sw = r & 7;
#pragma unroll
                for (int kc = 0; kc < 4; kc++) {
                    bf16x8 kf = *(const bf16x8*)(
                        Kb + r * 128 + (((kc * 4 + quad) ^ sw) << 3));
                    s = __builtin_amdgcn_mfma_f32_16x16x32_bf16(qf[kc], kf, s, 0, 0, 0);
                }
                sc[cbk] = s;
            }

            const int qrow = qb + wave * 16 + quad * 4;
            if (tk == nt - 1) {
#pragma unroll
                for (int rr = 0; rr < 4; rr++)
#pragma unroll
                    for (int cbk = 0; cbk < 4; cbk++) {
                        const int col = kv0 + cbk * 16 + l16;
                        const float v = sc[cbk][rr] * scale;
                        sc[cbk][rr] = (col > qrow + rr) ? NEG_BIG : v;
                    }
            } else {
#pragma unroll
                for (int rr = 0; rr < 4; rr++)
#pragma unroll
                    for (int cbk = 0; cbk < 4; cbk++) sc[cbk][rr] *= scale;
            }
            float mx[4];
#pragma unroll
            for (int rr = 0; rr < 4; rr++)
                mx[rr] = fmaxf(fmaxf(sc[0][rr], sc[1][rr]),
                               fmaxf(sc[2][rr], sc[3][rr]));
#pragma unroll
            for (int off = 1; off < 16; off <<= 1)
#pragma unroll
                for (int rr = 0; rr < 4; rr++)
                    mx[rr] = fmaxf(mx[rr], __shfl_xor(mx[rr], off));

            float alpha[4], rsum[4];
#pragma unroll
            for (int rr = 0; rr < 4; rr++) {
                const float mnew = fmaxf(m_i[rr], mx[rr]);
                alpha[rr] = __expf(m_i[rr] - mnew);
                m_i[rr] = mnew;
                float acc = 0.f;
#pragma unroll
                for (int cbk = 0; cbk < 4; cbk++) {
                    const float pv = __expf(sc[cbk][rr] - mnew);
                    sc[cbk][rr] = pv;
                    acc += pv;
                }
                rsum[rr] = acc;
            }
#pragma unroll
            for (int off = 1; off < 16; off <<= 1)
#pragma unroll
                for (int rr = 0; rr < 4; rr++)
                    rsum[rr] += __shfl_xor(rsum[rr], off);
#pragma unroll
            for (int rr = 0; rr < 4; rr++)
                l_i[rr] = l_i[rr] * alpha[rr] + rsum[rr];
#pragma unroll
            for (int ni = 0; ni < 8; ni++)
#pragma unroll
                for (int rr = 0; rr < 4; rr++) oacc[ni][rr] *= alpha[rr];

#pragma unroll
            for (int cbk = 0; cbk < 4; cbk++)
#pragma unroll
                for (int rr = 0; rr < 4; rr++) {
                    const int row = wave * 16 + quad * 4 + rr;
                    const int col = cbk * 16 + l16;
                    Pl[row * 64 + ((((col >> 3) ^ (row & 7)) << 3) | (col & 7))] =
                        __float2bfloat16(sc[cbk][rr]);
                }
            asm volatile("s_waitcnt lgkmcnt(0)" ::: "memory");

            const int prow = wave * 16 + l16;
            bf16x8 pf[2];
#pragma unroll
            for (int kc = 0; kc < 2; kc++)
                pf[kc] = *(const bf16x8*)(
                    Pl + prow * 64 + (((kc * 4 + quad) ^ (prow & 7)) << 3));
#pragma unroll
            for (int ni = 0; ni < 8; ni++) {
                const int vr = ni * 16 + l16;
#pragma unroll
                for (int kc = 0; kc < 2; kc++) {
                    bf16x8 vf = *(const bf16x8*)(
                        Vb + kc * 4096 + vr * 32 + (((quad ^ (vr & 3))) << 3));
                    oacc[ni] = __builtin_amdgcn_mfma_f32_16x16x32_bf16(
                        pf[kc], vf, oacc[ni], 0, 0, 0);
                }
            }

            asm volatile("" ::: "memory");
            __builtin_amdgcn_s_barrier();
            asm volatile("" ::: "memory");
        }

        float inv[4];
#pragma unroll
        for (int rr = 0; rr < 4; rr++) inv[rr] = 1.0f / l_i[rr];
#pragma unroll
        for (int ni = 0; ni < 8; ni++)
#pragma unroll
            for (int rr = 0; rr < 4; rr++) {
                const int row = qb + wave * 16 + quad * 4 + rr;
                O[((size_t)rowb + row) * 6144 + 4096 + h * 128 + ni * 16 + l16] =
                    __float2bfloat16(oacc[ni][rr] * inv[rr]);
            }
    }
}

// ============================================================================
extern "C" void kernel_launch(void* const* d_in, const int* in_sizes, int n_in,
                              void* d_out, int out_size, void* d_ws, size_t ws_size,
                              hipStream_t stream) {
    const float* query = (const float*)d_in[0];
    const float* Wqkv = (const float*)d_in[3];
    const float* bqkv = (const float*)d_in[4];
    const float* Wout = (const float*)d_in[5];
    const float* bout = (const float*)d_in[6];
    float* out = (float*)d_out;

    const size_t MB = 1048576;
    char* ws = (char*)d_ws;
    __hip_bfloat16* QKV = (__hip_bfloat16*)ws;
    __hip_bfloat16* Vpt = (__hip_bfloat16*)(ws + 48 * MB);
    __hip_bfloat16* Att = QKV + 4096;            // column offset, lda = 6144

    dim3 blk(256);

    if (ws_size >= 113 * MB) {
        __hip_bfloat16* Qbf     = (__hip_bfloat16*)(ws + 64 * MB);
        __hip_bfloat16* Wqkv_bf = (__hip_bfloat16*)(ws + 80 * MB);
        __hip_bfloat16* Wout_bf = (__hip_bfloat16*)(ws + 104 * MB);

        cvt3_f32_bf16<<<dim3(2048), blk, 0, stream>>>(
            query, (size_t)4096 * 2048 / 8,
            Wqkv,  (size_t)6144 * 2048 / 8,
            Wout,  (size_t)2048 * 2048 / 8,
            Qbf, Wqkv_bf, Wout_bf);
        // QKV projection: 128x192 tiles, grid 32x32 = 1024, 2 blocks/CU
        gemm2b_nt_bias<<<dim3(1024), dim3(256), 0, stream>>>(
            Qbf, Wqkv_bf, bqkv, QKV, 4096, 6144, 2048, 2048, 2048);
        permute_v<<<dim3(2048), blk, 0, stream>>>(QKV, Vpt);
        flash_attn<<<dim3(512), blk, 0, stream>>>(QKV, Vpt, QKV);
        // out projection: 128x256 tiles, grid 32x8 = 256 = exactly 1/CU
        gemm8p_nt_bias<true><<<dim3(256), dim3(512), 0, stream>>>(
            Att, Wout_bf, bout, out, 4096, 2048, 2048, 6144, 2048, 32);
    } else {
        gemm_nt_bias<true, true, false><<<dim3(48, 32), blk, 0, stream>>>(
            query, Wqkv, bqkv, QKV, 4096, 6144, 2048, 2048, 2048);
        permute_v<<<dim3(2048), blk, 0, stream>>>(QKV, Vpt);
        flash_attn<<<dim3(512), blk, 0, stream>>>(QKV, Vpt, QKV);
        gemm_nt_bias<false, true, true><<<dim3(16, 32), blk, 0, stream>>>(
            Att, Wout, bout, out, 4096, 2048, 2048, 6144, 2048);
    }
}

// Round 6
// 354.933 us; speedup vs baseline: 1.6486x; 1.0090x over previous
//
#include <hip/hip_runtime.h>
#include <hip/hip_bf16.h>
#include <stdint.h>

// ---- types ----
typedef __bf16 bf16x8 __attribute__((ext_vector_type(8)));
typedef float  floatx4 __attribute__((ext_vector_type(4)));

#define NEG_BIG (-1e30f)   // finite sentinel: exp(NEG_BIG - m) == 0

// async global->LDS, 16B per lane; LDS dest = wave-uniform base + lane*16
#define GLD16(g, l) __builtin_amdgcn_global_load_lds(                         \
    (__attribute__((address_space(1))) void*)(g),                             \
    (__attribute__((address_space(3))) void*)(l), 16, 0, 0)

// convert 16 fp32 -> 16 bf16, store 32B to LDS
__device__ __forceinline__ void cvt16(const float* __restrict__ s,
                                      __hip_bfloat16* __restrict__ d) {
    float4 f[4];
#pragma unroll
    for (int i = 0; i < 4; i++) f[i] = ((const float4*)s)[i];
    union { __hip_bfloat16 h[16]; uint4 u[2]; } o;
#pragma unroll
    for (int i = 0; i < 4; i++) {
        o.h[4 * i + 0] = __float2bfloat16(f[i].x);
        o.h[4 * i + 1] = __float2bfloat16(f[i].y);
        o.h[4 * i + 2] = __float2bfloat16(f[i].z);
        o.h[4 * i + 3] = __float2bfloat16(f[i].w);
    }
    ((uint4*)d)[0] = o.u[0];
    ((uint4*)d)[1] = o.u[1];
}

// ============================================================================
// Fused fp32->bf16 convert of up to 3 arrays (grid-stride, 8 elems/thread).
// ============================================================================
__global__ __launch_bounds__(256)
void cvt3_f32_bf16(const float* __restrict__ a, size_t na8,
                   const float* __restrict__ b, size_t nb8,
                   const float* __restrict__ c, size_t nc8,
                   __hip_bfloat16* __restrict__ da,
                   __hip_bfloat16* __restrict__ db,
                   __hip_bfloat16* __restrict__ dc)
{
    const size_t total  = na8 + nb8 + nc8;
    const size_t stride = (size_t)gridDim.x * blockDim.x;
    for (size_t idx = (size_t)blockIdx.x * blockDim.x + threadIdx.x;
         idx < total; idx += stride) {
        const float* s; __hip_bfloat16* d; size_t o;
        if (idx < na8)            { s = a; d = da; o = idx; }
        else if (idx < na8 + nb8) { s = b; d = db; o = idx - na8; }
        else                      { s = c; d = dc; o = idx - na8 - nb8; }
        const float4 f0 = ((const float4*)s)[o * 2 + 0];
        const float4 f1 = ((const float4*)s)[o * 2 + 1];
        union { __hip_bfloat16 h[8]; uint4 u; } z;
        z.h[0] = __float2bfloat16(f0.x); z.h[1] = __float2bfloat16(f0.y);
        z.h[2] = __float2bfloat16(f0.z); z.h[3] = __float2bfloat16(f0.w);
        z.h[4] = __float2bfloat16(f1.x); z.h[5] = __float2bfloat16(f1.y);
        z.h[6] = __float2bfloat16(f1.z); z.h[7] = __float2bfloat16(f1.w);
        ((uint4*)d)[o] = z.u;
    }
}

// ============================================================================
// 128x192-tile NT GEMM, 2 blocks/CU (QKV projection; verified R5 @1021 TF).
// 256 threads = 4 waves (2M x 2N), wave tile 64x96, acc[4][6]. BK=64.
// LDS = 2buf x (A 16KB + B 24KB) = 80KB -> exactly 2 blocks/CU. Counted
// vmcnt(5), both-sides XOR swizzle, setprio around MFMA. Grid 1024 = 32x32.
// See R4/R5 header comments for the dead-region/vmcnt proof.
// ============================================================================
__global__ __launch_bounds__(256, 2)
void gemm2b_nt_bias(const __hip_bfloat16* __restrict__ A,
                    const __hip_bfloat16* __restrict__ B,
                    const float* __restrict__ bias,
                    __hip_bfloat16* __restrict__ C,
                    int M, int N, int K, int lda, int ldb)
{
    __shared__ __align__(16) __hip_bfloat16 Asm[2][128 * 64];
    __shared__ __align__(16) __hip_bfloat16 Bsm[2][192 * 64];

    // 2D XCD chunk mapping (grid 1024 = 32 x 32)
    const int flat = blockIdx.x;
    const int c    = flat & 7;          // XCD (round-robin dispatch)
    const int i_   = flat >> 3;         // 0..127 within chunk
    const int by = (c & 1) * 16 + (i_ & 15);
    const int bx = (c >> 1) * 8 + (i_ >> 4);
    const int m0 = by * 128, n0 = bx * 192;

    const int t    = threadIdx.x;
    const int wave = t >> 6, lane = t & 63;
    const int quad = lane >> 4, l16 = lane & 15;
    const int wr   = wave >> 1, wc = wave & 1;   // wave tile 64x96
    const int NT   = K >> 6;

    const int l8 = lane >> 3;            // row within wave's 8-row slice
    const int g_ = (lane & 7) ^ l8;      // pre-swizzled source granule
    auto stageA = [&](int tk, int j, int buf) {
        GLD16(A + (size_t)(m0 + j * 32 + wave * 8 + l8) * lda + tk * 64 + g_ * 8,
              &Asm[buf][0] + (j * 32 + wave * 8) * 64);
    };
    auto stageB = [&](int tk, int j, int buf) {
        GLD16(B + (size_t)(n0 + j * 32 + wave * 8 + l8) * ldb + tk * 64 + g_ * 8,
              &Bsm[buf][0] + (j * 32 + wave * 8) * 64);
    };

    const int g0 = (quad ^ (l16 & 7)) << 3;   // element offset; ks flips ^32

    floatx4 acc[4][6];
    const floatx4 zero = {0.f, 0.f, 0.f, 0.f};
#pragma unroll
    for (int mi = 0; mi < 4; mi++)
#pragma unroll
        for (int ni = 0; ni < 6; ni++) acc[mi][ni] = zero;

#pragma unroll
    for (int j = 0; j < 4; j++) stageA(0, j, 0);
#pragma unroll
    for (int j = 0; j < 6; j++) stageB(0, j, 0);
    if (NT > 1) {
        stageA(1, 0, 1); stageA(1, 2, 1);
        stageB(1, 0, 1); stageB(1, 1, 1); stageB(1, 2, 1);
        asm volatile("s_waitcnt vmcnt(5)" ::: "memory");
    } else {
        asm volatile("s_waitcnt vmcnt(0)" ::: "memory");
    }
    __syncthreads();

    int cb = 0;
    for (int tk = 0; tk < NT; ++tk, cb ^= 1) {
        const __hip_bfloat16* Ab = &Asm[cb][0];
        const __hip_bfloat16* Bb = &Bsm[cb][0];
        const int nb = cb ^ 1;

        // ================= phase 0 : mi = 0,1 =================
        bf16x8 af[2][2], bfr[6][2];
#pragma unroll
        for (int i = 0; i < 2; i++)
#pragma unroll
            for (int ks = 0; ks < 2; ks++)
                af[i][ks] = *(const bf16x8*)(
                    Ab + (wr * 64 + i * 16 + l16) * 64 + (g0 ^ (ks ? 32 : 0)));
#pragma unroll
        for (int ni = 0; ni < 6; ni++)
#pragma unroll
            for (int ks = 0; ks < 2; ks++)
                bfr[ni][ks] = *(const bf16x8*)(
                    Bb + (wc * 96 + ni * 16 + l16) * 64 + (g0 ^ (ks ? 32 : 0)));
        if (tk + 1 < NT) {
            stageA(tk + 1, 1, nb); stageA(tk + 1, 3, nb);
            stageB(tk + 1, 3, nb); stageB(tk + 1, 4, nb); stageB(tk + 1, 5, nb);
        }
        __builtin_amdgcn_s_barrier();
        asm volatile("s_waitcnt lgkmcnt(0)" ::: "memory");
        __builtin_amdgcn_s_setprio(1);
#pragma unroll
        for (int ks = 0; ks < 2; ks++)
#pragma unroll
            for (int i = 0; i < 2; i++)
#pragma unroll
                for (int ni = 0; ni < 6; ni++)
                    acc[i][ni] = __builtin_amdgcn_mfma_f32_16x16x32_bf16(
                        af[i][ks], bfr[ni][ks], acc[i][ni], 0, 0, 0);
        __builtin_amdgcn_s_setprio(0);
        __builtin_amdgcn_s_barrier();

        // ================= phase 1 : mi = 2,3 =================
#pragma unroll
        for (int i = 0; i < 2; i++)
#pragma unroll
            for (int ks = 0; ks < 2; ks++)
                af[i][ks] = *(const bf16x8*)(
                    Ab + (wr * 64 + (2 + i) * 16 + l16) * 64 + (g0 ^ (ks ? 32 : 0)));
        if (tk + 2 < NT) {
            stageA(tk + 2, 0, cb); stageA(tk + 2, 2, cb);
            stageB(tk + 2, 0, cb); stageB(tk + 2, 1, cb); stageB(tk + 2, 2, cb);
        }
        __builtin_amdgcn_s_barrier();
        asm volatile("s_waitcnt lgkmcnt(0)" ::: "memory");
        __builtin_amdgcn_s_setprio(1);
#pragma unroll
        for (int ks = 0; ks < 2; ks++)
#pragma unroll
            for (int i = 0; i < 2; i++)
#pragma unroll
                for (int ni = 0; ni < 6; ni++)
                    acc[2 + i][ni] = __builtin_amdgcn_mfma_f32_16x16x32_bf16(
                        af[i][ks], bfr[ni][ks], acc[2 + i][ni], 0, 0, 0);
        __builtin_amdgcn_s_setprio(0);
        if (tk + 2 < NT)
            asm volatile("s_waitcnt vmcnt(5)" ::: "memory");
        else if (tk + 1 < NT)
            asm volatile("s_waitcnt vmcnt(0)" ::: "memory");
        __builtin_amdgcn_s_barrier();
    }

#pragma unroll
    for (int mi = 0; mi < 4; mi++) {
        const int row = m0 + wr * 64 + mi * 16 + quad * 4;
#pragma unroll
        for (int ni = 0; ni < 6; ni++) {
            const int col = n0 + wc * 96 + ni * 16 + l16;
            const float bv = bias[col];
#pragma unroll
            for (int r = 0; r < 4; r++)
                C[(size_t)(row + r) * N + col] =
                    __float2bfloat16(acc[mi][ni][r] + bv);
        }
    }
}

// ============================================================================
// 128x128-tile NT GEMM, 2 blocks/CU, f32 out (out-projection).
// Same schedule family as gemm2b: 256 threads = 4 waves (2M x 2N), wave tile
// 64x64, acc[4][4] -> 32 MFMA/wave/K-tile. LDS = 2buf x (A 16KB + B 16KB)
// = 64KB -> 2 blocks/CU. Grid 512 = 32by x 16bx = exactly 2/CU, zero tail.
// Replaces the 1-block/CU gemm8p (R5 proved 2-block overlap > lockstep).
//
// 2 phases/K-tile, 16 MFMA each:
//  p0: ds_read A(mi0,1) + B all (held in regs); stage TAIL(t+1)={A1,A3,B2,B3}
//      -> buf^1; bar; lgkm0; prio1; 16 MFMA; prio0; bar
//  p1: ds_read A(mi2,3); stage HEAD(t+2)={A0,A2,B0,B1} -> cur buf (dead:
//      A0/A2 rows consumed in p0 by wr=0/1; all B consumed in p0); bar;
//      lgkm0; prio1; 16 MFMA; prio0; [vmcnt(4)|vmcnt(0)]; bar
// In-flight at tile end = tail(t+1)[4] + head(t+2)[4] = 8; vmcnt(4) leaves
// head(t+2) in flight with t+1 fully resident. Never drains in-loop.
// XCD 2D chunk: c=flat&7 owns by in [(c&3)*8,+8), bx in [(c>>2)*8,+8).
// ============================================================================
__global__ __launch_bounds__(256, 2)
void gemm2b128_nt_bias(const __hip_bfloat16* __restrict__ A,
                       const __hip_bfloat16* __restrict__ B,
                       const float* __restrict__ bias,
                       float* __restrict__ C,
                       int M, int N, int K, int lda, int ldb)
{
    __shared__ __align__(16) __hip_bfloat16 Asm[2][128 * 64];
    __shared__ __align__(16) __hip_bfloat16 Bsm[2][128 * 64];

    const int flat = blockIdx.x;
    const int c    = flat & 7;
    const int i_   = flat >> 3;          // 0..63
    const int by = (c & 3) * 8 + (i_ & 7);
    const int bx = (c >> 2) * 8 + (i_ >> 3);
    const int m0 = by * 128, n0 = bx * 128;

    const int t    = threadIdx.x;
    const int wave = t >> 6, lane = t & 63;
    const int quad = lane >> 4, l16 = lane & 15;
    const int wr   = wave >> 1, wc = wave & 1;   // wave tile 64x64
    const int NT   = K >> 6;

    const int l8 = lane >> 3;
    const int g_ = (lane & 7) ^ l8;
    auto stageA = [&](int tk, int j, int buf) {
        GLD16(A + (size_t)(m0 + j * 32 + wave * 8 + l8) * lda + tk * 64 + g_ * 8,
              &Asm[buf][0] + (j * 32 + wave * 8) * 64);
    };
    auto stageB = [&](int tk, int j, int buf) {
        GLD16(B + (size_t)(n0 + j * 32 + wave * 8 + l8) * ldb + tk * 64 + g_ * 8,
              &Bsm[buf][0] + (j * 32 + wave * 8) * 64);
    };

    const int g0 = (quad ^ (l16 & 7)) << 3;

    floatx4 acc[4][4];
    const floatx4 zero = {0.f, 0.f, 0.f, 0.f};
#pragma unroll
    for (int mi = 0; mi < 4; mi++)
#pragma unroll
        for (int ni = 0; ni < 4; ni++) acc[mi][ni] = zero;

    // prologue: full t0 (8 loads) + head(t1) (4); vmcnt(4)
#pragma unroll
    for (int j = 0; j < 4; j++) stageA(0, j, 0);
#pragma unroll
    for (int j = 0; j < 4; j++) stageB(0, j, 0);
    if (NT > 1) {
        stageA(1, 0, 1); stageA(1, 2, 1); stageB(1, 0, 1); stageB(1, 1, 1);
        asm volatile("s_waitcnt vmcnt(4)" ::: "memory");
    } else {
        asm volatile("s_waitcnt vmcnt(0)" ::: "memory");
    }
    __syncthreads();

    int cb = 0;
    for (int tk = 0; tk < NT; ++tk, cb ^= 1) {
        const __hip_bfloat16* Ab = &Asm[cb][0];
        const __hip_bfloat16* Bb = &Bsm[cb][0];
        const int nb = cb ^ 1;

        // ================= phase 0 : mi = 0,1 =================
        bf16x8 af[2][2], bfr[4][2];
#pragma unroll
        for (int i = 0; i < 2; i++)
#pragma unroll
            for (int ks = 0; ks < 2; ks++)
                af[i][ks] = *(const bf16x8*)(
                    Ab + (wr * 64 + i * 16 + l16) * 64 + (g0 ^ (ks ? 32 : 0)));
#pragma unroll
        for (int ni = 0; ni < 4; ni++)
#pragma unroll
            for (int ks = 0; ks < 2; ks++)
                bfr[ni][ks] = *(const bf16x8*)(
                    Bb + (wc * 64 + ni * 16 + l16) * 64 + (g0 ^ (ks ? 32 : 0)));
        if (tk + 1 < NT) {
            stageA(tk + 1, 1, nb); stageA(tk + 1, 3, nb);
            stageB(tk + 1, 2, nb); stageB(tk + 1, 3, nb);
        }
        __builtin_amdgcn_s_barrier();
        asm volatile("s_waitcnt lgkmcnt(0)" ::: "memory");
        __builtin_amdgcn_s_setprio(1);
#pragma unroll
        for (int ks = 0; ks < 2; ks++)
#pragma unroll
            for (int i = 0; i < 2; i++)
#pragma unroll
                for (int ni = 0; ni < 4; ni++)
                    acc[i][ni] = __builtin_amdgcn_mfma_f32_16x16x32_bf16(
                        af[i][ks], bfr[ni][ks], acc[i][ni], 0, 0, 0);
        __builtin_amdgcn_s_setprio(0);
        __builtin_amdgcn_s_barrier();

        // ================= phase 1 : mi = 2,3 =================
#pragma unroll
        for (int i = 0; i < 2; i++)
#pragma unroll
            for (int ks = 0; ks < 2; ks++)
                af[i][ks] = *(const bf16x8*)(
                    Ab + (wr * 64 + (2 + i) * 16 + l16) * 64 + (g0 ^ (ks ? 32 : 0)));
        if (tk + 2 < NT) {
            stageA(tk + 2, 0, cb); stageA(tk + 2, 2, cb);
            stageB(tk + 2, 0, cb); stageB(tk + 2, 1, cb);
        }
        __builtin_amdgcn_s_barrier();
        asm volatile("s_waitcnt lgkmcnt(0)" ::: "memory");
        __builtin_amdgcn_s_setprio(1);
#pragma unroll
        for (int ks = 0; ks < 2; ks++)
#pragma unroll
            for (int i = 0; i < 2; i++)
#pragma unroll
                for (int ni = 0; ni < 4; ni++)
                    acc[2 + i][ni] = __builtin_amdgcn_mfma_f32_16x16x32_bf16(
                        af[i][ks], bfr[ni][ks], acc[2 + i][ni], 0, 0, 0);
        __builtin_amdgcn_s_setprio(0);
        if (tk + 2 < NT)
            asm volatile("s_waitcnt vmcnt(4)" ::: "memory");
        else if (tk + 1 < NT)
            asm volatile("s_waitcnt vmcnt(0)" ::: "memory");
        __builtin_amdgcn_s_barrier();
    }

#pragma unroll
    for (int mi = 0; mi < 4; mi++) {
        const int row = m0 + wr * 64 + mi * 16 + quad * 4;
#pragma unroll
        for (int ni = 0; ni < 4; ni++) {
            const int col = n0 + wc * 64 + ni * 16 + l16;
            const float bv = bias[col];
#pragma unroll
            for (int r = 0; r < 4; r++)
                C[(size_t)(row + r) * N + col] = acc[mi][ni][r] + bv;
        }
    }
}

// ============================================================================
// 128x128 NT GEMM (m97 structure) — fp32 fallback path only.
// ============================================================================
template <bool A_F32, bool B_F32, bool OUT_F32>
__global__ __launch_bounds__(256, 2)
void gemm_nt_bias(const void* __restrict__ Av, const void* __restrict__ Bv,
                  const float* __restrict__ bias, void* __restrict__ Cv,
                  int M, int N, int K, int lda, int ldb)
{
    __shared__ __align__(16) __hip_bfloat16 Asm[128 * 32];
    __shared__ __align__(16) __hip_bfloat16 Bsm[128 * 32];
    const int m0   = blockIdx.y * 128;
    const int n0   = blockIdx.x * 128;
    const int t    = threadIdx.x;
    const int wave = t >> 6, lane = t & 63;
    const int quad = lane >> 4, l16 = lane & 15;
    const int wr   = wave >> 1, wc = wave & 1;

    floatx4 zero = {0.f, 0.f, 0.f, 0.f};
    floatx4 acc[4][4];
    for (int i = 0; i < 4; i++)
        for (int j = 0; j < 4; j++) acc[i][j] = zero;

    for (int k0 = 0; k0 < K; k0 += 32) {
        if (A_F32) {
            const float* A = (const float*)Av;
            const int row = t >> 1, half = t & 1;
            cvt16(A + (size_t)(m0 + row) * lda + k0 + half * 16,
                  Asm + row * 32 + half * 16);
        } else {
            const __hip_bfloat16* A = (const __hip_bfloat16*)Av;
            for (int j = 0; j < 2; ++j) {
                const int chunk = (wave * 2 + j) * 64 + lane;
                const int row   = chunk >> 2;
                const int kc    = chunk & 3;
                GLD16(A + (size_t)(m0 + row) * lda + k0 + kc * 8,
                      Asm + (wave * 2 + j) * 512);
            }
        }
        if (B_F32) {
            const float* B = (const float*)Bv;
            const int row = t >> 1, half = t & 1;
            cvt16(B + (size_t)(n0 + row) * ldb + k0 + half * 16,
                  Bsm + row * 32 + half * 16);
        } else {
            const __hip_bfloat16* B = (const __hip_bfloat16*)Bv;
            for (int j = 0; j < 2; ++j) {
                const int chunk = (wave * 2 + j) * 64 + lane;
                const int row   = chunk >> 2;
                const int kc    = chunk & 3;
                GLD16(B + (size_t)(n0 + row) * ldb + k0 + kc * 8,
                      Bsm + (wave * 2 + j) * 512);
            }
        }
        __syncthreads();

        bf16x8 af[4], bf[4];
        for (int i = 0; i < 4; i++) {
            af[i] = *(const bf16x8*)(Asm + (wr * 64 + i * 16 + l16) * 32 + quad * 8);
            bf[i] = *(const bf16x8*)(Bsm + (wc * 64 + i * 16 + l16) * 32 + quad * 8);
        }
        for (int mi = 0; mi < 4; mi++)
            for (int ni = 0; ni < 4; ni++)
                acc[mi][ni] = __builtin_amdgcn_mfma_f32_16x16x32_bf16(
                    af[mi], bf[ni], acc[mi][ni], 0, 0, 0);
        __syncthreads();
    }

    for (int mi = 0; mi < 4; mi++) {
        const int row = m0 + wr * 64 + mi * 16 + quad * 4;
        for (int ni = 0; ni < 4; ni++) {
            const int col = n0 + wc * 64 + ni * 16 + l16;
            const float bv = bias[col];
            for (int r = 0; r < 4; r++) {
                const float v = acc[mi][ni][r] + bv;
                if (OUT_F32)
                    ((float*)Cv)[(size_t)(row + r) * N + col] = v;
                else
                    ((__hip_bfloat16*)Cv)[(size_t)(row + r) * N + col] =
                        __float2bfloat16(v);
            }
        }
    }
}

// ============================================================================
// V permutation (unchanged): Vpt[b][h][sb32][hd][ss32], 8KB blobs.
// ============================================================================
__global__ __launch_bounds__(256)
void permute_v(const __hip_bfloat16* __restrict__ QKV,
               __hip_bfloat16* __restrict__ Vpt)
{
    __shared__ __align__(16) __hip_bfloat16 S[64 * 64];
    const int blk = blockIdx.x;
    const int sb = blk & 31, h = (blk >> 5) & 15, b = blk >> 9;
    const int t = threadIdx.x;

    for (int j = 0; j < 2; j++) {
        const int chunk = j * 256 + t;
        const int lrow  = chunk >> 3;
        const int lcol  = (chunk & 7) * 8;
        const int r8 = lrow >> 3, jj = lrow & 7;
        const int srow = r8 * 128 + h * 8 + jj;
        const int scol = sb * 64 + lcol;
        *(uint4*)(S + chunk * 8) =
            *(const uint4*)(QKV + ((size_t)(b * 1024) + srow) * 6144 + 4096 + scol);
    }
    __syncthreads();

    const size_t obase = (((size_t)(b * 16 + h)) * 32 + sb) * 4096;
    for (int i = 0; i < 16; i++) {
        const int lin = t + 256 * i;
        const int hd = lin >> 5, ss = lin & 31;
        Vpt[obase + lin] =
            S[((ss & 7) * 8 + (hd >> 4)) * 64 + (ss >> 3) * 16 + (hd & 15)];
    }
}

// ============================================================================
// Causal flash attention v3: v2 + defer-max (THR=8, T13) + deferred l-sum
// reduction (per-thread partials, one shuffle-reduce in epilogue).
// l_i is now a per-thread partial over this lane's 4 columns per tile;
// reduced across the 16-lane row group only at the end.
// Defer-max: when no row's tile-max exceeds m_i+8 (wave-uniform __any),
// keep m_i, skip the 32-mul oacc rescale; P bounded by e^8 (f32/bf16 safe).
// ============================================================================
__global__ __launch_bounds__(256, 2)
void flash_attn(const __hip_bfloat16* __restrict__ QKV,
                const __hip_bfloat16* __restrict__ Vpt,
                __hip_bfloat16* __restrict__ O)   // == QKV buffer
{
    __shared__ __align__(16) __hip_bfloat16 Kt[2][64 * 128];
    __shared__ __align__(16) __hip_bfloat16 Vt[2][2 * 128 * 32];
    __shared__ __align__(16) __hip_bfloat16 Pl[64 * 64];

    const int bid  = blockIdx.x;
    const int pair = bid >> 6;
    const int g    = bid & 63;
    const int b    = g >> 4, h = g & 15;
    const int t    = threadIdx.x;
    const int wave = t >> 6, lane = t & 63;
    const int quad = lane >> 4, l16 = lane & 15;
    const float scale = 0.08838834764831845f;

    const int    rowb  = b * 1024;
    const size_t vbase = (((size_t)(b * 16 + h)) * 32) * 4096;
    const floatx4 zero = {0.f, 0.f, 0.f, 0.f};

    auto stageK = [&](int tk, int bufi) {
        const int kv0 = tk * 64;
        __hip_bfloat16* dst = &Kt[bufi][0];
#pragma unroll
        for (int j = 0; j < 4; j++) {
            const int c0 = (wave * 4 + j) * 64 + lane;
            const int r  = c0 >> 4;
            const int gg = (c0 & 15) ^ (r & 7);
            GLD16(QKV + ((size_t)(rowb + kv0 + r)) * 6144 + 2048 + h * 128 + gg * 8,
                  dst + (wave * 4 + j) * 512);
        }
    };
    auto stageV = [&](int tk, int bufi) {
        const __hip_bfloat16* src = Vpt + vbase + (size_t)(tk * 2) * 4096;
        __hip_bfloat16* dst = &Vt[bufi][0];
#pragma unroll
        for (int j = 0; j < 4; j++) {
            const int c0   = (wave * 4 + j) * 64 + lane;
            const int half = c0 >> 9, w = c0 & 511;
            const int r    = w >> 2;
            const int gg   = (w & 3) ^ (r & 3);
            GLD16(src + half * 4096 + r * 32 + gg * 8,
                  dst + (wave * 4 + j) * 512);
        }
    };

    for (int ph = 0; ph < 2; ++ph) {
        const int qb = ph ? (15 - pair) * 64 : pair * 64;
        const int nt = ph ? 16 - pair       : pair + 1;

        bf16x8 qf[4];
        {
            const size_t rb = ((size_t)(rowb + qb + wave * 16 + l16)) * 6144 + h * 128;
#pragma unroll
            for (int kc = 0; kc < 4; kc++)
                qf[kc] = *(const bf16x8*)(QKV + rb + kc * 32 + quad * 8);
        }

        float m_i[4], l_i[4];    // l_i: per-thread partial (this lane's cols)
        floatx4 oacc[8];
#pragma unroll
        for (int r = 0; r < 4; r++) { m_i[r] = NEG_BIG; l_i[r] = 0.f; }
#pragma unroll
        for (int ni = 0; ni < 8; ni++) oacc[ni] = zero;

        stageK(0, 0); stageV(0, 0);

        for (int tk = 0; tk < nt; ++tk) {
            const int cur = tk & 1;
            if (tk + 1 < nt) {
                stageK(tk + 1, cur ^ 1); stageV(tk + 1, cur ^ 1);
                asm volatile("s_waitcnt vmcnt(8)" ::: "memory");
            } else {
                asm volatile("s_waitcnt vmcnt(0)" ::: "memory");
            }
            __builtin_amdgcn_s_barrier();
            asm volatile("" ::: "memory");

            const __hip_bfloat16* Kb = &Kt[cur][0];
            const __hip_bfloat16* Vb = &Vt[cur][0];
            const int kv0 = tk * 64;

            floatx4 sc[4];
#pragma unroll
            for (int cbk = 0; cbk < 4; cbk++) {
                floatx4 s = zero;
                const int r  = cbk * 16 + l16;
                const int sw = r & 7;
#pragma unroll
                for (int kc = 0; kc < 4; kc++) {
                    bf16x8 kf = *(const bf16x8*)(
                        Kb + r * 128 + (((kc * 4 + quad) ^ sw) << 3));
                    s = __builtin_amdgcn_mfma_f32_16x16x32_bf16(qf[kc], kf, s, 0, 0, 0);
                }
                sc[cbk] = s;
            }

            const int qrow = qb + wave * 16 + quad * 4;
            if (tk == nt - 1) {
#pragma unroll
                for (int rr = 0; rr < 4; rr++)
#pragma unroll
                    for (int cbk = 0; cbk < 4; cbk++) {
                        const int col = kv0 + cbk * 16 + l16;
                        const float v = sc[cbk][rr] * scale;
                        sc[cbk][rr] = (col > qrow + rr) ? NEG_BIG : v;
                    }
            } else {
#pragma unroll
                for (int rr = 0; rr < 4; rr++)
#pragma unroll
                    for (int cbk = 0; cbk < 4; cbk++) sc[cbk][rr] *= scale;
            }
            float mx[4];
#pragma unroll
            for (int rr = 0; rr < 4; rr++)
                mx[rr] = fmaxf(fmaxf(sc[0][rr], sc[1][rr]),
                               fmaxf(sc[2][rr], sc[3][rr]));
#pragma unroll
            for (int off = 1; off < 16; off <<= 1)
#pragma unroll
                for (int rr = 0; rr < 4; rr++)
                    mx[rr] = fmaxf(mx[rr], __shfl_xor(mx[rr], off));

            // ---- defer-max: rescale only when some row grew past m_i+8 ----
            bool grow = false;
#pragma unroll
            for (int rr = 0; rr < 4; rr++)
                grow = grow || (mx[rr] > m_i[rr] + 8.0f);
            if (__any((int)grow)) {
#pragma unroll
                for (int rr = 0; rr < 4; rr++) {
                    const float mnew  = fmaxf(m_i[rr], mx[rr]);
                    const float alpha = __expf(m_i[rr] - mnew);
                    m_i[rr] = mnew;
                    float lsum = 0.f;
#pragma unroll
                    for (int cbk = 0; cbk < 4; cbk++) {
                        const float pv = __expf(sc[cbk][rr] - mnew);
                        sc[cbk][rr] = pv;
                        lsum += pv;
                    }
                    l_i[rr] = l_i[rr] * alpha + lsum;
#pragma unroll
                    for (int ni = 0; ni < 8; ni++) oacc[ni][rr] *= alpha;
                }
            } else {
#pragma unroll
                for (int rr = 0; rr < 4; rr++) {
                    float lsum = 0.f;
#pragma unroll
                    for (int cbk = 0; cbk < 4; cbk++) {
                        const float pv = __expf(sc[cbk][rr] - m_i[rr]);
                        sc[cbk][rr] = pv;
                        lsum += pv;
                    }
                    l_i[rr] += lsum;
                }
            }

#pragma unroll
            for (int cbk = 0; cbk < 4; cbk++)
#pragma unroll
                for (int rr = 0; rr < 4; rr++) {
                    const int row = wave * 16 + quad * 4 + rr;
                    const int col = cbk * 16 + l16;
                    Pl[row * 64 + ((((col >> 3) ^ (row & 7)) << 3) | (col & 7))] =
                        __float2bfloat16(sc[cbk][rr]);
                }
            asm volatile("s_waitcnt lgkmcnt(0)" ::: "memory");

            const int prow = wave * 16 + l16;
            bf16x8 pf[2];
#pragma unroll
            for (int kc = 0; kc < 2; kc++)
                pf[kc] = *(const bf16x8*)(
                    Pl + prow * 64 + (((kc * 4 + quad) ^ (prow & 7)) << 3));
#pragma unroll
            for (int ni = 0; ni < 8; ni++) {
                const int vr = ni * 16 + l16;
#pragma unroll
                for (int kc = 0; kc < 2; kc++) {
                    bf16x8 vf = *(const bf16x8*)(
                        Vb + kc * 4096 + vr * 32 + (((quad ^ (vr & 3))) << 3));
                    oacc[ni] = __builtin_amdgcn_mfma_f32_16x16x32_bf16(
                        pf[kc], vf, oacc[ni], 0, 0, 0);
                }
            }

            asm volatile("" ::: "memory");
            __builtin_amdgcn_s_barrier();
            asm volatile("" ::: "memory");
        }

        // ---- deferred l reduction (16-lane row groups), then epilogue ----
#pragma unroll
        for (int off = 1; off < 16; off <<= 1)
#pragma unroll
            for (int rr = 0; rr < 4; rr++)
                l_i[rr] += __shfl_xor(l_i[rr], off);
        float inv[4];
#pragma unroll
        for (int rr = 0; rr < 4; rr++) inv[rr] = 1.0f / l_i[rr];
#pragma unroll
        for (int ni = 0; ni < 8; ni++)
#pragma unroll
            for (int rr = 0; rr < 4; rr++) {
                const int row = qb + wave * 16 + quad * 4 + rr;
                O[((size_t)rowb + row) * 6144 + 4096 + h * 128 + ni * 16 + l16] =
                    __float2bfloat16(oacc[ni][rr] * inv[rr]);
            }
    }
}

// ============================================================================
extern "C" void kernel_launch(void* const* d_in, const int* in_sizes, int n_in,
                              void* d_out, int out_size, void* d_ws, size_t ws_size,
                              hipStream_t stream) {
    const float* query = (const float*)d_in[0];
    const float* Wqkv = (const float*)d_in[3];
    const float* bqkv = (const float*)d_in[4];
    const float* Wout = (const float*)d_in[5];
    const float* bout = (const float*)d_in[6];
    float* out = (float*)d_out;

    const size_t MB = 1048576;
    char* ws = (char*)d_ws;
    __hip_bfloat16* QKV = (__hip_bfloat16*)ws;
    __hip_bfloat16* Vpt = (__hip_bfloat16*)(ws + 48 * MB);
    __hip_bfloat16* Att = QKV + 4096;            // column offset, lda = 6144

    dim3 blk(256);

    if (ws_size >= 113 * MB) {
        __hip_bfloat16* Qbf     = (__hip_bfloat16*)(ws + 64 * MB);
        __hip_bfloat16* Wqkv_bf = (__hip_bfloat16*)(ws + 80 * MB);
        __hip_bfloat16* Wout_bf = (__hip_bfloat16*)(ws + 104 * MB);

        cvt3_f32_bf16<<<dim3(2048), blk, 0, stream>>>(
            query, (size_t)4096 * 2048 / 8,
            Wqkv,  (size_t)6144 * 2048 / 8,
            Wout,  (size_t)2048 * 2048 / 8,
            Qbf, Wqkv_bf, Wout_bf);
        // QKV projection: 128x192 tiles, grid 32x32 = 1024, 2 blocks/CU
        gemm2b_nt_bias<<<dim3(1024), dim3(256), 0, stream>>>(
            Qbf, Wqkv_bf, bqkv, QKV, 4096, 6144, 2048, 2048, 2048);
        permute_v<<<dim3(2048), blk, 0, stream>>>(QKV, Vpt);
        flash_attn<<<dim3(512), blk, 0, stream>>>(QKV, Vpt, QKV);
        // out projection: 128x128 tiles, grid 32x16 = 512 = exactly 2/CU
        gemm2b128_nt_bias<<<dim3(512), dim3(256), 0, stream>>>(
            Att, Wout_bf, bout, out, 4096, 2048, 2048, 6144, 2048);
    } else {
        gemm_nt_bias<true, true, false><<<dim3(48, 32), blk, 0, stream>>>(
            query, Wqkv, bqkv, QKV, 4096, 6144, 2048, 2048, 2048);
        permute_v<<<dim3(2048), blk, 0, stream>>>(QKV, Vpt);
        flash_attn<<<dim3(512), blk, 0, stream>>>(QKV, Vpt, QKV);
        gemm_nt_bias<false, true, true><<<dim3(16, 32), blk, 0, stream>>>(
            Att, Wout, bout, out, 4096, 2048, 2048, 6144, 2048);
    }
}